// Round 1
// baseline (1800.531 us; speedup 1.0000x reference)
//
#include <hip/hip_runtime.h>

#define N_OBJ  20000
#define N_ROOM 500
#define N_ATTR 2000
#define IN_F   300
#define HDIM   512
#define E_OO   640000
#define E_RO   50000
#define E_AO   100000
#define BATCH  8

typedef __attribute__((ext_vector_type(8))) __bf16 bf16x8;
typedef __attribute__((ext_vector_type(4))) float  f32x4;

// ---- float -> bf16 (round-to-nearest-even), as raw bits ----
__device__ inline unsigned short f2bf_rn(float x)
{
    unsigned u = __float_as_uint(x);
    unsigned r = (u + 0x7fffu + ((u >> 16) & 1u)) >> 16;
    return (unsigned short)r;
}
__device__ inline float bf2f(unsigned short h)
{
    return __uint_as_float(((unsigned)h) << 16);
}

// async global->LDS, 16 B per lane (global addr per-lane, LDS base wave-uniform)
__device__ inline void gload16(const unsigned short* g, unsigned short* l)
{
    __builtin_amdgcn_global_load_lds(
        (const __attribute__((address_space(1))) void*)g,
        (__attribute__((address_space(3))) void*)l,
        16, 0, 0);
}

// ---------------------------------------------------------------------------
// Degree counting (all 3 relations in one grid)
// ---------------------------------------------------------------------------
__global__ void count_edges(const int* __restrict__ src_oo, const int* __restrict__ dst_oo,
                            const int* __restrict__ src_ro, const int* __restrict__ dst_ro,
                            const int* __restrict__ src_ao, const int* __restrict__ dst_ao,
                            int* cnt_src_oo, int* cnt_src_ro, int* cnt_src_ao,
                            int* cnt_dst_oo, int* cnt_dst_ro, int* cnt_dst_ao)
{
    int e = blockIdx.x * blockDim.x + threadIdx.x;
    const int total = E_OO + E_RO + E_AO;
    if (e >= total) return;
    if (e < E_OO) {
        atomicAdd(&cnt_src_oo[src_oo[e]], 1);
        atomicAdd(&cnt_dst_oo[dst_oo[e]], 1);
    } else if (e < E_OO + E_RO) {
        int i = e - E_OO;
        atomicAdd(&cnt_src_ro[src_ro[i]], 1);
        atomicAdd(&cnt_dst_ro[dst_ro[i]], 1);
    } else {
        int i = e - E_OO - E_RO;
        atomicAdd(&cnt_src_ao[src_ao[i]], 1);
        atomicAdd(&cnt_dst_ao[dst_ao[i]], 1);
    }
}

// ---------------------------------------------------------------------------
// Exclusive prefix-sum of the 3 dst-degree arrays
// ---------------------------------------------------------------------------
__global__ __launch_bounds__(1024)
void scan3(const int* c0, const int* c1, const int* c2,
           int* r0, int* r1, int* r2,
           int* u0, int* u1, int* u2)
{
    const int n = N_OBJ;
    const int* cnt = (blockIdx.x == 0) ? c0 : (blockIdx.x == 1 ? c1 : c2);
    int* rp  = (blockIdx.x == 0) ? r0 : (blockIdx.x == 1 ? r1 : r2);
    int* cur = (blockIdx.x == 0) ? u0 : (blockIdx.x == 1 ? u1 : u2);

    __shared__ int part[1024];
    int t  = threadIdx.x;
    int lo = t * 20;
    int hi = lo + 20 < n ? lo + 20 : n;

    int local = 0;
    for (int i = lo; i < hi; ++i) local += cnt[i];
    part[t] = local;
    __syncthreads();
    for (int off = 1; off < 1024; off <<= 1) {
        int v = (t >= off) ? part[t - off] : 0;
        __syncthreads();
        part[t] += v;
        __syncthreads();
    }
    int run = part[t] - local;
    for (int i = lo; i < hi; ++i) {
        rp[i]  = run;
        cur[i] = run;
        run += cnt[i];
    }
    if (t == 1023) rp[n] = part[1023];
}

// ---------------------------------------------------------------------------
// norm = 1/sqrt(max(deg,1)) for the 6 degree arrays
// ---------------------------------------------------------------------------
__global__ void norms6(const int* c0, const int* c1, const int* c2,
                       const int* c3, const int* c4, const int* c5,
                       float* n0, float* n1, float* n2,
                       float* n3, float* n4, float* n5,
                       int s0, int s1, int s2, int s3, int s4, int s5)
{
    const int* c; float* o; int n;
    switch (blockIdx.y) {
        case 0:  c = c0; o = n0; n = s0; break;
        case 1:  c = c1; o = n1; n = s1; break;
        case 2:  c = c2; o = n2; n = s2; break;
        case 3:  c = c3; o = n3; n = s3; break;
        case 4:  c = c4; o = n4; n = s4; break;
        default: c = c5; o = n5; n = s5; break;
    }
    int i = blockIdx.x * blockDim.x + threadIdx.x;
    if (i < n) {
        int d = c[i];
        if (d < 1) d = 1;
        o[i] = 1.0f / sqrtf((float)d);
    }
}

// ---------------------------------------------------------------------------
// Fill CSR column arrays using atomic cursors
// ---------------------------------------------------------------------------
__global__ void fill_edges(const int* __restrict__ src_oo, const int* __restrict__ dst_oo,
                           const int* __restrict__ src_ro, const int* __restrict__ dst_ro,
                           const int* __restrict__ src_ao, const int* __restrict__ dst_ao,
                           int* cur_oo, int* cur_ro, int* cur_ao,
                           int* col_oo, int* col_ro, int* col_ao)
{
    int e = blockIdx.x * blockDim.x + threadIdx.x;
    const int total = E_OO + E_RO + E_AO;
    if (e >= total) return;
    if (e < E_OO) {
        int pos = atomicAdd(&cur_oo[dst_oo[e]], 1);
        col_oo[pos] = src_oo[e];
    } else if (e < E_OO + E_RO) {
        int i = e - E_OO;
        int pos = atomicAdd(&cur_ro[dst_ro[i]], 1);
        col_ro[pos] = src_ro[i];
    } else {
        int i = e - E_OO - E_RO;
        int pos = atomicAdd(&cur_ao[dst_ao[i]], 1);
        col_ao[pos] = src_ao[i];
    }
}

// ---------------------------------------------------------------------------
// Pack weight: Wp is n-major [HDIM][3*Kp] bf16 bits, rows: [Wh | Wl | Wh]
// ---------------------------------------------------------------------------
__global__ void pack_w(const float* __restrict__ W, int K, int Kp,
                       unsigned short* __restrict__ Wp)
{
    int Keff = 3 * Kp;
    int idx = blockIdx.x * 256 + threadIdx.x;
    if (idx >= HDIM * Keff) return;
    int n  = idx / Keff;
    int kp = idx - n * Keff;
    int term = (kp >= 2 * Kp) ? 2 : (kp >= Kp ? 1 : 0);
    int ks = kp - term * Kp;
    float v = (ks < K) ? W[(size_t)ks * HDIM + n] : 0.0f;
    unsigned short h = f2bf_rn(v);
    unsigned short out = (term == 1) ? f2bf_rn(v - bf2f(h)) : h;
    Wp[idx] = out;
}

// ---------------------------------------------------------------------------
// XCD-pinned column-chunked CSR aggregation with bf16 hi/lo split output.
// chunk = blockIdx.x & 7 (== XCD via round-robin dispatch): each XCD's L2
// only ever sees a CW-column slice of feat (3.2-5.1 MB -> L2-resident).
// One wave per (dst, chunk); 128-thread blocks = 2 waves = 2 dst nodes.
// 1-deep software pipeline on the col->nsrc/feat dependent chain.
// 8*CW == Fp; pad cols (cc >= F) written as 0.
// ---------------------------------------------------------------------------
__global__ __launch_bounds__(128)
void agg_chunk(const float* __restrict__ feat, int F, int Fp, int CW,
               const int* __restrict__ rp, const int* __restrict__ col,
               const float* __restrict__ nsrc, const float* __restrict__ ndst,
               float scale,
               unsigned short* __restrict__ hi, unsigned short* __restrict__ lo)
{
    int c0 = (blockIdx.x & 7) * CW;
    int d  = ((blockIdx.x >> 3) << 1) + (threadIdx.x >> 6);
    int t  = threadIdx.x & 63;
    int cc = c0 + t;
    bool act  = (t < CW);
    bool real = act && (cc < F);

    int a = rp[d], b = rp[d + 1];
    int n = b - a;
    float acc = 0.f;

    int   s_nx = (n > 0) ? col[a] : 0;
    float f_nx = (real && n > 0) ? feat[(size_t)s_nx * F + cc] : 0.f;
    float w_nx = (n > 0) ? nsrc[s_nx] * scale : 0.f;
    for (int i = 0; i < n; ++i) {
        float fc = f_nx, wc = w_nx;
        int i1 = i + 1;
        if (i1 < n) {
            int s1 = col[a + i1];
            f_nx = real ? feat[(size_t)s1 * F + cc] : 0.f;
            w_nx = nsrc[s1] * scale;
        }
        acc += fc * wc;
    }

    if (act) {
        float v = real ? acc * ndst[d] : 0.f;
        size_t o = (size_t)d * Fp + cc;
        unsigned short h = f2bf_rn(v);
        hi[o] = h;
        lo[o] = f2bf_rn(v - bf2f(h));
    }
}

// ---------------------------------------------------------------------------
// bf16 MFMA GEMM: C[M x 512] = epi( (Ah+Al) @ (Wh+Wl) + bias ), split into
// K_eff = 3*Kp: [0,Kp)=Ah@Wh, [Kp,2Kp)=Ah@Wl, [2Kp,3Kp)=Al@Wh.
// Wp is n-major [512][3Kp]. Block 256 thr = 4 waves, tile 128x128, BK=32.
// Staging via global_load_lds width=16 (m97 pattern): LDT=32 (no pad) makes
// the LDS tile gl_lds-linear; fragment reads touch each bank exactly 8x per
// wave (b128 minimum) -> conflict-free without swizzle.
// Last m-tile reads OOB garbage A rows (stays inside ws scratch); those
// output rows are discarded by the m<M guard.
// 1D grid + bijective m204 XCD swizzle: the 4 n-tiles sharing an A panel
// run on one XCD -> A re-reads served from L2.
// EPI: 0 = C=relu(v), 1 = C+=relu(v), 2 = out[0..7 slices]=v, 3 = C=v
// ---------------------------------------------------------------------------
template<int EPI>
__global__ __launch_bounds__(256)
void gemm_mfma(const unsigned short* __restrict__ Ah,
               const unsigned short* __restrict__ Al,
               const unsigned short* __restrict__ Wp,
               const float* __restrict__ bias,
               float* __restrict__ C,
               int M, int Kp, int nwg)
{
    __shared__ unsigned short As[128 * 32];
    __shared__ unsigned short Bs[128 * 32];

    // bijective XCD-chunk swizzle (m204)
    int orig = blockIdx.x;
    int qq8 = nwg >> 3, r8 = nwg & 7, xcd = orig & 7;
    int w = (xcd < r8 ? xcd * (qq8 + 1) : r8 * (qq8 + 1) + (xcd - r8) * qq8) + (orig >> 3);
    int m0 = (w >> 2) * 128;
    int n0 = (w & 3) * 128;

    int tid  = threadIdx.x;
    int lane = tid & 63;
    int wave = tid >> 6;
    int wm = (wave & 1) * 64;
    int wn = (wave >> 1) * 64;
    int Keff = 3 * Kp;
    int rw = lane & 15;                     // fragment row index
    int q  = lane >> 4;                     // k-group

    int rb  = wave * 32;                    // this wave's staging rows
    int rl  = lane >> 2;                    // 0..15 row within 16-row group
    int klo = (lane & 3) * 8;               // shorts within the 32-short row

    f32x4 acc[4][4];
#pragma unroll
    for (int i = 0; i < 4; ++i)
#pragma unroll
        for (int j = 0; j < 4; ++j) acc[i][j] = (f32x4)0.0f;

    for (int k0 = 0; k0 < Keff; k0 += 32) {
        int term = (k0 >= 2 * Kp) ? 2 : (k0 >= Kp ? 1 : 0);
        int kb = k0 - ((term == 2) ? 2 * Kp : (term == 1 ? Kp : 0));
        const unsigned short* Asrc = (term == 2) ? Al : Ah;

        gload16(Asrc + (size_t)(m0 + rb + rl) * Kp + kb + klo,        &As[rb * 32]);
        gload16(Asrc + (size_t)(m0 + rb + 16 + rl) * Kp + kb + klo,   &As[(rb + 16) * 32]);
        gload16(Wp   + (size_t)(n0 + rb + rl) * Keff + k0 + klo,      &Bs[rb * 32]);
        gload16(Wp   + (size_t)(n0 + rb + 16 + rl) * Keff + k0 + klo, &Bs[(rb + 16) * 32]);
        __syncthreads();                     // drains vmcnt -> LDS tiles ready

        bf16x8 af[4], bfr[4];
#pragma unroll
        for (int i = 0; i < 4; ++i) {
            af[i]  = __builtin_bit_cast(bf16x8, *(const uint4*)&As[(wm + i * 16 + rw) * 32 + q * 8]);
            bfr[i] = __builtin_bit_cast(bf16x8, *(const uint4*)&Bs[(wn + i * 16 + rw) * 32 + q * 8]);
        }
#pragma unroll
        for (int i = 0; i < 4; ++i)
#pragma unroll
            for (int j = 0; j < 4; ++j)
                acc[i][j] = __builtin_amdgcn_mfma_f32_16x16x32_bf16(af[i], bfr[j], acc[i][j], 0, 0, 0);
        __syncthreads();
    }

    // epilogue: D row = q*4 + r, col = rw (within each 16x16 frag)
    const size_t slice = (size_t)N_OBJ * HDIM;
#pragma unroll
    for (int j = 0; j < 4; ++j) {
        int n = n0 + wn + j * 16 + rw;
        float bv = bias[n];
#pragma unroll
        for (int i = 0; i < 4; ++i) {
#pragma unroll
            for (int r = 0; r < 4; ++r) {
                int m = m0 + wm + i * 16 + q * 4 + r;
                if (m < M) {
                    float v = acc[i][j][r] + bv;
                    size_t o = (size_t)m * HDIM + n;
                    if (EPI == 0)      C[o] = fmaxf(v, 0.f);
                    else if (EPI == 1) C[o] += fmaxf(v, 0.f);
                    else if (EPI == 2) {
#pragma unroll
                        for (int c = 0; c < BATCH; ++c) C[c * slice + o] = v;
                    } else             C[o] = v;
                }
            }
        }
    }
}

// ---------------------------------------------------------------------------
// Broadcast slice 0 of d_out into slices 1..7 (fallback path only)
// ---------------------------------------------------------------------------
__global__ void bcast8(const float4* __restrict__ src, float4* __restrict__ dst)
{
    const long long slice4 = (long long)N_OBJ * HDIM / 4;
    long long i = (long long)blockIdx.x * blockDim.x + threadIdx.x;
    float4 v = src[i];
#pragma unroll
    for (int c = 1; c < BATCH; ++c)
        dst[c * slice4 + i] = v;
}

// ---------------------------------------------------------------------------
extern "C" void kernel_launch(void* const* d_in, const int* in_sizes, int n_in,
                              void* d_out, int out_size, void* d_ws, size_t ws_size,
                              hipStream_t stream)
{
    const float* feat_object = (const float*)d_in[1];
    const float* feat_room   = (const float*)d_in[2];
    const float* feat_attr   = (const float*)d_in[3];
    const float* W1i = (const float*)d_in[4];
    const float* b1i = (const float*)d_in[5];
    const float* W1b = (const float*)d_in[6];
    const float* b1b = (const float*)d_in[7];
    const float* W2  = (const float*)d_in[8];
    const float* b2  = (const float*)d_in[9];
    const int* src_oo = (const int*)d_in[10];
    const int* dst_oo = (const int*)d_in[11];
    const int* src_ro = (const int*)d_in[12];
    const int* dst_ro = (const int*)d_in[13];
    const int* src_ao = (const int*)d_in[14];
    const int* dst_ao = (const int*)d_in[15];
    float* out = (float*)d_out;

    const size_t slice = (size_t)N_OBJ * HDIM;
    const int KP1 = 320;                 // 300 padded to 32; 8 chunks x 40
    const int KP2 = 512;                 // 8 chunks x 64

    const size_t NEED = 130u * 1024u * 1024u;
    bool use_ws = (ws_size >= NEED);
    char* base = use_ws ? (char*)d_ws : (char*)(out + slice);
    size_t off = 0;
    auto alloc = [&](size_t bytes) -> void* {
        void* p = base + off;
        off += (bytes + 255) & ~(size_t)255;
        return p;
    };

    float* n_src_oo = (float*)alloc(N_OBJ  * 4);
    float* n_src_ro = (float*)alloc(N_ROOM * 4);
    float* n_src_ao = (float*)alloc(N_ATTR * 4);
    float* n_dst_oo = (float*)alloc(N_OBJ * 4);
    float* n_dst_ro = (float*)alloc(N_OBJ * 4);
    float* n_dst_ao = (float*)alloc(N_OBJ * 4);

    const int CNT_TOTAL = N_OBJ + 512 + 2048 + 3 * N_OBJ;
    int* cnt_blk    = (int*)alloc((size_t)CNT_TOTAL * 4);
    int* cnt_src_oo = cnt_blk;
    int* cnt_src_ro = cnt_src_oo + N_OBJ;
    int* cnt_src_ao = cnt_src_ro + 512;
    int* cnt_dst_oo = cnt_src_ao + 2048;
    int* cnt_dst_ro = cnt_dst_oo + N_OBJ;
    int* cnt_dst_ao = cnt_dst_ro + N_OBJ;

    int* rp_oo  = (int*)alloc((N_OBJ + 1) * 4);
    int* rp_ro  = (int*)alloc((N_OBJ + 1) * 4);
    int* rp_ao  = (int*)alloc((N_OBJ + 1) * 4);
    int* cur_oo = (int*)alloc(N_OBJ * 4);
    int* cur_ro = (int*)alloc(N_OBJ * 4);
    int* cur_ao = (int*)alloc(N_OBJ * 4);
    int* col_oo = (int*)alloc((size_t)E_OO * 4);
    int* col_ro = (int*)alloc((size_t)E_RO * 4);
    int* col_ao = (int*)alloc((size_t)E_AO * 4);

    unsigned short* Ah1 = (unsigned short*)alloc((size_t)N_OBJ * KP1 * 2);
    unsigned short* Al1 = (unsigned short*)alloc((size_t)N_OBJ * KP1 * 2);
    unsigned short* Ah2 = (unsigned short*)alloc((size_t)N_OBJ * KP2 * 2);
    unsigned short* Al2 = (unsigned short*)alloc((size_t)N_OBJ * KP2 * 2);
    unsigned short* Wp1i = (unsigned short*)alloc((size_t)HDIM * 3 * KP1 * 2);
    unsigned short* Wp1b = (unsigned short*)alloc((size_t)HDIM * 3 * KP1 * 2);
    unsigned short* Wp2  = (unsigned short*)alloc((size_t)HDIM * 3 * KP2 * 2);
    float* h_sum = (float*)alloc(slice * 4);

    // ---- CSR build ----
    hipMemsetAsync(cnt_blk, 0, (size_t)CNT_TOTAL * 4, stream);
    const int TOTAL_E = E_OO + E_RO + E_AO;
    int egrid = (TOTAL_E + 255) / 256;
    count_edges<<<egrid, 256, 0, stream>>>(src_oo, dst_oo, src_ro, dst_ro, src_ao, dst_ao,
                                           cnt_src_oo, cnt_src_ro, cnt_src_ao,
                                           cnt_dst_oo, cnt_dst_ro, cnt_dst_ao);
    scan3<<<3, 1024, 0, stream>>>(cnt_dst_oo, cnt_dst_ro, cnt_dst_ao,
                                  rp_oo, rp_ro, rp_ao, cur_oo, cur_ro, cur_ao);
    norms6<<<dim3((N_OBJ + 255) / 256, 6), 256, 0, stream>>>(
        cnt_src_oo, cnt_src_ro, cnt_src_ao, cnt_dst_oo, cnt_dst_ro, cnt_dst_ao,
        n_src_oo, n_src_ro, n_src_ao, n_dst_oo, n_dst_ro, n_dst_ao,
        N_OBJ, N_ROOM, N_ATTR, N_OBJ, N_OBJ, N_OBJ);
    fill_edges<<<egrid, 256, 0, stream>>>(src_oo, dst_oo, src_ro, dst_ro, src_ao, dst_ao,
                                          cur_oo, cur_ro, cur_ao, col_oo, col_ro, col_ao);

    // ---- weight packing (hi/lo split, n-major) ----
    {
        int e1 = HDIM * 3 * KP1, e2 = HDIM * 3 * KP2;
        pack_w<<<(e1 + 255) / 256, 256, 0, stream>>>(W1i, IN_F, KP1, Wp1i);
        pack_w<<<(e1 + 255) / 256, 256, 0, stream>>>(W1b, IN_F, KP1, Wp1b);
        pack_w<<<(e2 + 255) / 256, 256, 0, stream>>>(W2, HDIM, KP2, Wp2);
    }

    const int AGG_GRID = (N_OBJ / 2) * 8;          // 2 dst per block x 8 chunks
    int mt = (N_OBJ + 127) / 128;
    int nwg = mt * 4;                              // 1D GEMM grid (m204 swizzle)

    // ---- conv1 (three relations, relu-then-sum into h_sum) ----
    agg_chunk<<<AGG_GRID, 128, 0, stream>>>(feat_object, IN_F, KP1, KP1 / 8, rp_oo, col_oo,
                                            n_src_oo, n_dst_oo, 1.0f, Ah1, Al1);
    gemm_mfma<0><<<nwg, 256, 0, stream>>>(Ah1, Al1, Wp1i, b1i, h_sum, N_OBJ, KP1, nwg);

    agg_chunk<<<AGG_GRID, 128, 0, stream>>>(feat_room, IN_F, KP1, KP1 / 8, rp_ro, col_ro,
                                            n_src_ro, n_dst_ro, 1.0f, Ah1, Al1);
    gemm_mfma<1><<<nwg, 256, 0, stream>>>(Ah1, Al1, Wp1i, b1i, h_sum, N_OBJ, KP1, nwg);

    agg_chunk<<<AGG_GRID, 128, 0, stream>>>(feat_attr, IN_F, KP1, KP1 / 8, rp_ao, col_ao,
                                            n_src_ao, n_dst_ao, 1.0f, Ah1, Al1);
    gemm_mfma<1><<<nwg, 256, 0, stream>>>(Ah1, Al1, Wp1b, b1b, h_sum, N_OBJ, KP1, nwg);

    // ---- conv2 (oo graph on h_obj = h_sum/3; scale folded into agg) ----
    agg_chunk<<<AGG_GRID, 128, 0, stream>>>(h_sum, HDIM, KP2, KP2 / 8, rp_oo, col_oo,
                                            n_src_oo, n_dst_oo, 1.0f / 3.0f, Ah2, Al2);
    if (use_ws) {
        gemm_mfma<2><<<nwg, 256, 0, stream>>>(Ah2, Al2, Wp2, b2, out, N_OBJ, KP2, nwg);
    } else {
        gemm_mfma<3><<<nwg, 256, 0, stream>>>(Ah2, Al2, Wp2, b2, out, N_OBJ, KP2, nwg);
        const long long slice4 = (long long)slice / 4;
        bcast8<<<(unsigned)(slice4 / 256), 256, 0, stream>>>((const float4*)out, (float4*)out);
    }
}

// Round 2
// 1144.578 us; speedup vs baseline: 1.5731x; 1.5731x over previous
//
#include <hip/hip_runtime.h>

#define N_OBJ  20000
#define N_ROOM 500
#define N_ATTR 2000
#define IN_F   300
#define HDIM   512
#define E_OO   640000
#define E_RO   50000
#define E_AO   100000
#define BATCH  8

typedef __attribute__((ext_vector_type(8))) __bf16 bf16x8;
typedef __attribute__((ext_vector_type(4))) float  f32x4;

// ---- float -> bf16 (round-to-nearest-even), as raw bits ----
__device__ inline unsigned short f2bf_rn(float x)
{
    unsigned u = __float_as_uint(x);
    unsigned r = (u + 0x7fffu + ((u >> 16) & 1u)) >> 16;
    return (unsigned short)r;
}
__device__ inline float bf2f(unsigned short h)
{
    return __uint_as_float(((unsigned)h) << 16);
}

// async global->LDS, 16 B per lane (global addr per-lane, LDS base wave-uniform)
__device__ inline void gload16(const unsigned short* g, unsigned short* l)
{
    __builtin_amdgcn_global_load_lds(
        (const __attribute__((address_space(1))) void*)g,
        (__attribute__((address_space(3))) void*)l,
        16, 0, 0);
}

// ---------------------------------------------------------------------------
// Degree counting (all 3 relations in one grid)
// ---------------------------------------------------------------------------
__global__ void count_edges(const int* __restrict__ src_oo, const int* __restrict__ dst_oo,
                            const int* __restrict__ src_ro, const int* __restrict__ dst_ro,
                            const int* __restrict__ src_ao, const int* __restrict__ dst_ao,
                            int* cnt_src_oo, int* cnt_src_ro, int* cnt_src_ao,
                            int* cnt_dst_oo, int* cnt_dst_ro, int* cnt_dst_ao)
{
    int e = blockIdx.x * blockDim.x + threadIdx.x;
    const int total = E_OO + E_RO + E_AO;
    if (e >= total) return;
    if (e < E_OO) {
        atomicAdd(&cnt_src_oo[src_oo[e]], 1);
        atomicAdd(&cnt_dst_oo[dst_oo[e]], 1);
    } else if (e < E_OO + E_RO) {
        int i = e - E_OO;
        atomicAdd(&cnt_src_ro[src_ro[i]], 1);
        atomicAdd(&cnt_dst_ro[dst_ro[i]], 1);
    } else {
        int i = e - E_OO - E_RO;
        atomicAdd(&cnt_src_ao[src_ao[i]], 1);
        atomicAdd(&cnt_dst_ao[dst_ao[i]], 1);
    }
}

// ---------------------------------------------------------------------------
// Exclusive prefix-sum of the 3 dst-degree arrays
// ---------------------------------------------------------------------------
__global__ __launch_bounds__(1024)
void scan3(const int* c0, const int* c1, const int* c2,
           int* r0, int* r1, int* r2,
           int* u0, int* u1, int* u2)
{
    const int n = N_OBJ;
    const int* cnt = (blockIdx.x == 0) ? c0 : (blockIdx.x == 1 ? c1 : c2);
    int* rp  = (blockIdx.x == 0) ? r0 : (blockIdx.x == 1 ? r1 : r2);
    int* cur = (blockIdx.x == 0) ? u0 : (blockIdx.x == 1 ? u1 : u2);

    __shared__ int part[1024];
    int t  = threadIdx.x;
    int lo = t * 20;
    int hi = lo + 20 < n ? lo + 20 : n;

    int local = 0;
    for (int i = lo; i < hi; ++i) local += cnt[i];
    part[t] = local;
    __syncthreads();
    for (int off = 1; off < 1024; off <<= 1) {
        int v = (t >= off) ? part[t - off] : 0;
        __syncthreads();
        part[t] += v;
        __syncthreads();
    }
    int run = part[t] - local;
    for (int i = lo; i < hi; ++i) {
        rp[i]  = run;
        cur[i] = run;
        run += cnt[i];
    }
    if (t == 1023) rp[n] = part[1023];
}

// ---------------------------------------------------------------------------
// norm = 1/sqrt(max(deg,1)) for the 6 degree arrays
// ---------------------------------------------------------------------------
__global__ void norms6(const int* c0, const int* c1, const int* c2,
                       const int* c3, const int* c4, const int* c5,
                       float* n0, float* n1, float* n2,
                       float* n3, float* n4, float* n5,
                       int s0, int s1, int s2, int s3, int s4, int s5)
{
    const int* c; float* o; int n;
    switch (blockIdx.y) {
        case 0:  c = c0; o = n0; n = s0; break;
        case 1:  c = c1; o = n1; n = s1; break;
        case 2:  c = c2; o = n2; n = s2; break;
        case 3:  c = c3; o = n3; n = s3; break;
        case 4:  c = c4; o = n4; n = s4; break;
        default: c = c5; o = n5; n = s5; break;
    }
    int i = blockIdx.x * blockDim.x + threadIdx.x;
    if (i < n) {
        int d = c[i];
        if (d < 1) d = 1;
        o[i] = 1.0f / sqrtf((float)d);
    }
}

// ---------------------------------------------------------------------------
// Fill CSR column arrays using atomic cursors
// ---------------------------------------------------------------------------
__global__ void fill_edges(const int* __restrict__ src_oo, const int* __restrict__ dst_oo,
                           const int* __restrict__ src_ro, const int* __restrict__ dst_ro,
                           const int* __restrict__ src_ao, const int* __restrict__ dst_ao,
                           int* cur_oo, int* cur_ro, int* cur_ao,
                           int* col_oo, int* col_ro, int* col_ao)
{
    int e = blockIdx.x * blockDim.x + threadIdx.x;
    const int total = E_OO + E_RO + E_AO;
    if (e >= total) return;
    if (e < E_OO) {
        int pos = atomicAdd(&cur_oo[dst_oo[e]], 1);
        col_oo[pos] = src_oo[e];
    } else if (e < E_OO + E_RO) {
        int i = e - E_OO;
        int pos = atomicAdd(&cur_ro[dst_ro[i]], 1);
        col_ro[pos] = src_ro[i];
    } else {
        int i = e - E_OO - E_RO;
        int pos = atomicAdd(&cur_ao[dst_ao[i]], 1);
        col_ao[pos] = src_ao[i];
    }
}

// ---------------------------------------------------------------------------
// Pack weight: Wp is n-major [HDIM][3*Kp] bf16 bits, rows: [Wh | Wl | Wh]
// ---------------------------------------------------------------------------
__global__ void pack_w(const float* __restrict__ W, int K, int Kp,
                       unsigned short* __restrict__ Wp)
{
    int Keff = 3 * Kp;
    int idx = blockIdx.x * 256 + threadIdx.x;
    if (idx >= HDIM * Keff) return;
    int n  = idx / Keff;
    int kp = idx - n * Keff;
    int term = (kp >= 2 * Kp) ? 2 : (kp >= Kp ? 1 : 0);
    int ks = kp - term * Kp;
    float v = (ks < K) ? W[(size_t)ks * HDIM + n] : 0.0f;
    unsigned short h = f2bf_rn(v);
    unsigned short out = (term == 1) ? f2bf_rn(v - bf2f(h)) : h;
    Wp[idx] = out;
}

// ---------------------------------------------------------------------------
// CSR aggregation with bf16 hi/lo split output. Block = one dst node,
// 256 threads cover the full feature row (cols t and 256+t).
// 2-deep software pipeline on the dependent gather chain:
//   col[a+j+2] issued 2 iters ahead; nsrc / feat-row values 1 iter ahead.
// Accumulation order identical to the verified round-0 kernel (numerics
// bit-match). Pad cols written as 0.
// ---------------------------------------------------------------------------
__global__ __launch_bounds__(256)
void agg_csr_split(const float* __restrict__ feat, int F, int Fp,
                   const int* __restrict__ rp, const int* __restrict__ col,
                   const float* __restrict__ nsrc, const float* __restrict__ ndst,
                   float scale,
                   unsigned short* __restrict__ hi, unsigned short* __restrict__ lo)
{
    int d = blockIdx.x;
    int t = threadIdx.x;
    int a = rp[d], b = rp[d + 1];
    int n = b - a;
    int f2 = 256 + t;
    bool has2  = (f2 < Fp);
    bool real2 = (f2 < F);
    float acc0 = 0.f, acc1 = 0.f;

    // pipeline state: sj1 = col for iter j+1 (issued at j-1);
    // w/q0/q1 = values for iter j (issued at j-1)
    int   sj1 = (1 < n) ? col[a + 1] : 0;
    int   s0  = (0 < n) ? col[a] : 0;
    float w   = (0 < n) ? nsrc[s0] * scale : 0.f;
    float q0  = (0 < n) ? feat[(size_t)s0 * F + t] : 0.f;
    float q1  = (0 < n && real2) ? feat[(size_t)s0 * F + f2] : 0.f;

    for (int j = 0; j < n; ++j) {
        float fc0 = q0, fc1 = q1, wc = w;
        int snext = sj1;
        sj1 = (j + 2 < n) ? col[a + j + 2] : 0;   // depth-2 index prefetch
        if (j + 1 < n) {                           // depth-1 value prefetch
            w  = nsrc[snext] * scale;
            q0 = feat[(size_t)snext * F + t];
            q1 = real2 ? feat[(size_t)snext * F + f2] : 0.f;
        }
        acc0 += fc0 * wc;
        acc1 += fc1 * wc;
    }

    float nd = ndst[d];
    acc0 *= nd;
    acc1 = real2 ? acc1 * nd : 0.f;

    size_t o0 = (size_t)d * Fp + t;
    unsigned short h0 = f2bf_rn(acc0);
    hi[o0] = h0;
    lo[o0] = f2bf_rn(acc0 - bf2f(h0));
    if (has2) {
        size_t o1 = (size_t)d * Fp + f2;
        unsigned short h1 = f2bf_rn(acc1);
        hi[o1] = h1;
        lo[o1] = f2bf_rn(acc1 - bf2f(h1));
    }
}

// ---------------------------------------------------------------------------
// bf16 MFMA GEMM: C[M x 512] = epi( (Ah+Al) @ (Wh+Wl) + bias ), split into
// K_eff = 3*Kp: [0,Kp)=Ah@Wh, [Kp,2Kp)=Ah@Wl, [2Kp,3Kp)=Al@Wh.
// Wp is n-major [512][3Kp]. Block 256 thr = 4 waves, tile 128x128, BK=32.
// Staging via global_load_lds width=16 (m97 pattern): LDT=32 (no pad) makes
// the LDS tile gl_lds-linear; fragment reads touch each bank exactly 8x per
// wave (b128 minimum) -> conflict-free without swizzle.
// Last m-tile reads OOB garbage A rows (stays inside ws scratch); those
// output rows are discarded by the m<M guard.
// 1D grid + bijective m204 XCD swizzle.
// EPI: 0 = C=relu(v), 1 = C+=relu(v), 2 = out[0..7 slices]=v, 3 = C=v
// ---------------------------------------------------------------------------
template<int EPI>
__global__ __launch_bounds__(256)
void gemm_mfma(const unsigned short* __restrict__ Ah,
               const unsigned short* __restrict__ Al,
               const unsigned short* __restrict__ Wp,
               const float* __restrict__ bias,
               float* __restrict__ C,
               int M, int Kp, int nwg)
{
    __shared__ unsigned short As[128 * 32];
    __shared__ unsigned short Bs[128 * 32];

    // bijective XCD-chunk swizzle (m204)
    int orig = blockIdx.x;
    int qq8 = nwg >> 3, r8 = nwg & 7, xcd = orig & 7;
    int w = (xcd < r8 ? xcd * (qq8 + 1) : r8 * (qq8 + 1) + (xcd - r8) * qq8) + (orig >> 3);
    int m0 = (w >> 2) * 128;
    int n0 = (w & 3) * 128;

    int tid  = threadIdx.x;
    int lane = tid & 63;
    int wave = tid >> 6;
    int wm = (wave & 1) * 64;
    int wn = (wave >> 1) * 64;
    int Keff = 3 * Kp;
    int rw = lane & 15;                     // fragment row index
    int q  = lane >> 4;                     // k-group

    int rb  = wave * 32;                    // this wave's staging rows
    int rl  = lane >> 2;                    // 0..15 row within 16-row group
    int klo = (lane & 3) * 8;               // shorts within the 32-short row

    f32x4 acc[4][4];
#pragma unroll
    for (int i = 0; i < 4; ++i)
#pragma unroll
        for (int j = 0; j < 4; ++j) acc[i][j] = (f32x4)0.0f;

    for (int k0 = 0; k0 < Keff; k0 += 32) {
        int term = (k0 >= 2 * Kp) ? 2 : (k0 >= Kp ? 1 : 0);
        int kb = k0 - ((term == 2) ? 2 * Kp : (term == 1 ? Kp : 0));
        const unsigned short* Asrc = (term == 2) ? Al : Ah;

        gload16(Asrc + (size_t)(m0 + rb + rl) * Kp + kb + klo,        &As[rb * 32]);
        gload16(Asrc + (size_t)(m0 + rb + 16 + rl) * Kp + kb + klo,   &As[(rb + 16) * 32]);
        gload16(Wp   + (size_t)(n0 + rb + rl) * Keff + k0 + klo,      &Bs[rb * 32]);
        gload16(Wp   + (size_t)(n0 + rb + 16 + rl) * Keff + k0 + klo, &Bs[(rb + 16) * 32]);
        __syncthreads();                     // drains vmcnt -> LDS tiles ready

        bf16x8 af[4], bfr[4];
#pragma unroll
        for (int i = 0; i < 4; ++i) {
            af[i]  = __builtin_bit_cast(bf16x8, *(const uint4*)&As[(wm + i * 16 + rw) * 32 + q * 8]);
            bfr[i] = __builtin_bit_cast(bf16x8, *(const uint4*)&Bs[(wn + i * 16 + rw) * 32 + q * 8]);
        }
#pragma unroll
        for (int i = 0; i < 4; ++i)
#pragma unroll
            for (int j = 0; j < 4; ++j)
                acc[i][j] = __builtin_amdgcn_mfma_f32_16x16x32_bf16(af[i], bfr[j], acc[i][j], 0, 0, 0);
        __syncthreads();
    }

    // epilogue: D row = q*4 + r, col = rw (within each 16x16 frag)
    const size_t slice = (size_t)N_OBJ * HDIM;
#pragma unroll
    for (int j = 0; j < 4; ++j) {
        int n = n0 + wn + j * 16 + rw;
        float bv = bias[n];
#pragma unroll
        for (int i = 0; i < 4; ++i) {
#pragma unroll
            for (int r = 0; r < 4; ++r) {
                int m = m0 + wm + i * 16 + q * 4 + r;
                if (m < M) {
                    float v = acc[i][j][r] + bv;
                    size_t o = (size_t)m * HDIM + n;
                    if (EPI == 0)      C[o] = fmaxf(v, 0.f);
                    else if (EPI == 1) C[o] += fmaxf(v, 0.f);
                    else if (EPI == 2) {
#pragma unroll
                        for (int c = 0; c < BATCH; ++c) C[c * slice + o] = v;
                    } else             C[o] = v;
                }
            }
        }
    }
}

// ---------------------------------------------------------------------------
// Broadcast slice 0 of d_out into slices 1..7 (fallback path only)
// ---------------------------------------------------------------------------
__global__ void bcast8(const float4* __restrict__ src, float4* __restrict__ dst)
{
    const long long slice4 = (long long)N_OBJ * HDIM / 4;
    long long i = (long long)blockIdx.x * blockDim.x + threadIdx.x;
    float4 v = src[i];
#pragma unroll
    for (int c = 1; c < BATCH; ++c)
        dst[c * slice4 + i] = v;
}

// ---------------------------------------------------------------------------
extern "C" void kernel_launch(void* const* d_in, const int* in_sizes, int n_in,
                              void* d_out, int out_size, void* d_ws, size_t ws_size,
                              hipStream_t stream)
{
    const float* feat_object = (const float*)d_in[1];
    const float* feat_room   = (const float*)d_in[2];
    const float* feat_attr   = (const float*)d_in[3];
    const float* W1i = (const float*)d_in[4];
    const float* b1i = (const float*)d_in[5];
    const float* W1b = (const float*)d_in[6];
    const float* b1b = (const float*)d_in[7];
    const float* W2  = (const float*)d_in[8];
    const float* b2  = (const float*)d_in[9];
    const int* src_oo = (const int*)d_in[10];
    const int* dst_oo = (const int*)d_in[11];
    const int* src_ro = (const int*)d_in[12];
    const int* dst_ro = (const int*)d_in[13];
    const int* src_ao = (const int*)d_in[14];
    const int* dst_ao = (const int*)d_in[15];
    float* out = (float*)d_out;

    const size_t slice = (size_t)N_OBJ * HDIM;
    const int KP1 = 320;                 // 300 padded to 32
    const int KP2 = 512;

    const size_t NEED = 130u * 1024u * 1024u;
    bool use_ws = (ws_size >= NEED);
    char* base = use_ws ? (char*)d_ws : (char*)(out + slice);
    size_t off = 0;
    auto alloc = [&](size_t bytes) -> void* {
        void* p = base + off;
        off += (bytes + 255) & ~(size_t)255;
        return p;
    };

    float* n_src_oo = (float*)alloc(N_OBJ  * 4);
    float* n_src_ro = (float*)alloc(N_ROOM * 4);
    float* n_src_ao = (float*)alloc(N_ATTR * 4);
    float* n_dst_oo = (float*)alloc(N_OBJ * 4);
    float* n_dst_ro = (float*)alloc(N_OBJ * 4);
    float* n_dst_ao = (float*)alloc(N_OBJ * 4);

    const int CNT_TOTAL = N_OBJ + 512 + 2048 + 3 * N_OBJ;
    int* cnt_blk    = (int*)alloc((size_t)CNT_TOTAL * 4);
    int* cnt_src_oo = cnt_blk;
    int* cnt_src_ro = cnt_src_oo + N_OBJ;
    int* cnt_src_ao = cnt_src_ro + 512;
    int* cnt_dst_oo = cnt_src_ao + 2048;
    int* cnt_dst_ro = cnt_dst_oo + N_OBJ;
    int* cnt_dst_ao = cnt_dst_ro + N_OBJ;

    int* rp_oo  = (int*)alloc((N_OBJ + 1) * 4);
    int* rp_ro  = (int*)alloc((N_OBJ + 1) * 4);
    int* rp_ao  = (int*)alloc((N_OBJ + 1) * 4);
    int* cur_oo = (int*)alloc(N_OBJ * 4);
    int* cur_ro = (int*)alloc(N_OBJ * 4);
    int* cur_ao = (int*)alloc(N_OBJ * 4);
    int* col_oo = (int*)alloc((size_t)E_OO * 4);
    int* col_ro = (int*)alloc((size_t)E_RO * 4);
    int* col_ao = (int*)alloc((size_t)E_AO * 4);

    unsigned short* Ah1 = (unsigned short*)alloc((size_t)N_OBJ * KP1 * 2);
    unsigned short* Al1 = (unsigned short*)alloc((size_t)N_OBJ * KP1 * 2);
    unsigned short* Ah2 = (unsigned short*)alloc((size_t)N_OBJ * KP2 * 2);
    unsigned short* Al2 = (unsigned short*)alloc((size_t)N_OBJ * KP2 * 2);
    unsigned short* Wp1i = (unsigned short*)alloc((size_t)HDIM * 3 * KP1 * 2);
    unsigned short* Wp1b = (unsigned short*)alloc((size_t)HDIM * 3 * KP1 * 2);
    unsigned short* Wp2  = (unsigned short*)alloc((size_t)HDIM * 3 * KP2 * 2);
    float* h_sum = (float*)alloc(slice * 4);

    // ---- CSR build ----
    hipMemsetAsync(cnt_blk, 0, (size_t)CNT_TOTAL * 4, stream);
    const int TOTAL_E = E_OO + E_RO + E_AO;
    int egrid = (TOTAL_E + 255) / 256;
    count_edges<<<egrid, 256, 0, stream>>>(src_oo, dst_oo, src_ro, dst_ro, src_ao, dst_ao,
                                           cnt_src_oo, cnt_src_ro, cnt_src_ao,
                                           cnt_dst_oo, cnt_dst_ro, cnt_dst_ao);
    scan3<<<3, 1024, 0, stream>>>(cnt_dst_oo, cnt_dst_ro, cnt_dst_ao,
                                  rp_oo, rp_ro, rp_ao, cur_oo, cur_ro, cur_ao);
    norms6<<<dim3((N_OBJ + 255) / 256, 6), 256, 0, stream>>>(
        cnt_src_oo, cnt_src_ro, cnt_src_ao, cnt_dst_oo, cnt_dst_ro, cnt_dst_ao,
        n_src_oo, n_src_ro, n_src_ao, n_dst_oo, n_dst_ro, n_dst_ao,
        N_OBJ, N_ROOM, N_ATTR, N_OBJ, N_OBJ, N_OBJ);
    fill_edges<<<egrid, 256, 0, stream>>>(src_oo, dst_oo, src_ro, dst_ro, src_ao, dst_ao,
                                          cur_oo, cur_ro, cur_ao, col_oo, col_ro, col_ao);

    // ---- weight packing (hi/lo split, n-major) ----
    {
        int e1 = HDIM * 3 * KP1, e2 = HDIM * 3 * KP2;
        pack_w<<<(e1 + 255) / 256, 256, 0, stream>>>(W1i, IN_F, KP1, Wp1i);
        pack_w<<<(e1 + 255) / 256, 256, 0, stream>>>(W1b, IN_F, KP1, Wp1b);
        pack_w<<<(e2 + 255) / 256, 256, 0, stream>>>(W2, HDIM, KP2, Wp2);
    }

    int mt = (N_OBJ + 127) / 128;
    int nwg = mt * 4;                              // 1D GEMM grid (m204 swizzle)

    // ---- conv1 (three relations, relu-then-sum into h_sum) ----
    agg_csr_split<<<N_OBJ, 256, 0, stream>>>(feat_object, IN_F, KP1, rp_oo, col_oo,
                                             n_src_oo, n_dst_oo, 1.0f, Ah1, Al1);
    gemm_mfma<0><<<nwg, 256, 0, stream>>>(Ah1, Al1, Wp1i, b1i, h_sum, N_OBJ, KP1, nwg);

    agg_csr_split<<<N_OBJ, 256, 0, stream>>>(feat_room, IN_F, KP1, rp_ro, col_ro,
                                             n_src_ro, n_dst_ro, 1.0f, Ah1, Al1);
    gemm_mfma<1><<<nwg, 256, 0, stream>>>(Ah1, Al1, Wp1i, b1i, h_sum, N_OBJ, KP1, nwg);

    agg_csr_split<<<N_OBJ, 256, 0, stream>>>(feat_attr, IN_F, KP1, rp_ao, col_ao,
                                             n_src_ao, n_dst_ao, 1.0f, Ah1, Al1);
    gemm_mfma<1><<<nwg, 256, 0, stream>>>(Ah1, Al1, Wp1b, b1b, h_sum, N_OBJ, KP1, nwg);

    // ---- conv2 (oo graph on h_obj = h_sum/3; scale folded into agg) ----
    agg_csr_split<<<N_OBJ, 256, 0, stream>>>(h_sum, HDIM, KP2, rp_oo, col_oo,
                                             n_src_oo, n_dst_oo, 1.0f / 3.0f, Ah2, Al2);
    if (use_ws) {
        gemm_mfma<2><<<nwg, 256, 0, stream>>>(Ah2, Al2, Wp2, b2, out, N_OBJ, KP2, nwg);
    } else {
        gemm_mfma<3><<<nwg, 256, 0, stream>>>(Ah2, Al2, Wp2, b2, out, N_OBJ, KP2, nwg);
        const long long slice4 = (long long)slice / 4;
        bcast8<<<(unsigned)(slice4 / 256), 256, 0, stream>>>((const float4*)out, (float4*)out);
    }
}

// Round 3
// 993.120 us; speedup vs baseline: 1.8130x; 1.1525x over previous
//
#include <hip/hip_runtime.h>

#define N_OBJ  20000
#define N_ROOM 500
#define N_ATTR 2000
#define IN_F   300
#define HDIM   512
#define E_OO   640000
#define E_RO   50000
#define E_AO   100000
#define BATCH  8

typedef __attribute__((ext_vector_type(8))) __bf16 bf16x8;
typedef __attribute__((ext_vector_type(4))) float  f32x4;

// ---- float -> bf16 (round-to-nearest-even), as raw bits ----
__device__ inline unsigned short f2bf_rn(float x)
{
    unsigned u = __float_as_uint(x);
    unsigned r = (u + 0x7fffu + ((u >> 16) & 1u)) >> 16;
    return (unsigned short)r;
}
__device__ inline float bf2f(unsigned short h)
{
    return __uint_as_float(((unsigned)h) << 16);
}

// async global->LDS, 16 B per lane (global addr per-lane, LDS base wave-uniform)
__device__ inline void gload16(const unsigned short* g, unsigned short* l)
{
    __builtin_amdgcn_global_load_lds(
        (const __attribute__((address_space(1))) void*)g,
        (__attribute__((address_space(3))) void*)l,
        16, 0, 0);
}

// ---------------------------------------------------------------------------
// Degree counting (all 3 relations in one grid)
// ---------------------------------------------------------------------------
__global__ void count_edges(const int* __restrict__ src_oo, const int* __restrict__ dst_oo,
                            const int* __restrict__ src_ro, const int* __restrict__ dst_ro,
                            const int* __restrict__ src_ao, const int* __restrict__ dst_ao,
                            int* cnt_src_oo, int* cnt_src_ro, int* cnt_src_ao,
                            int* cnt_dst_oo, int* cnt_dst_ro, int* cnt_dst_ao)
{
    int e = blockIdx.x * blockDim.x + threadIdx.x;
    const int total = E_OO + E_RO + E_AO;
    if (e >= total) return;
    if (e < E_OO) {
        atomicAdd(&cnt_src_oo[src_oo[e]], 1);
        atomicAdd(&cnt_dst_oo[dst_oo[e]], 1);
    } else if (e < E_OO + E_RO) {
        int i = e - E_OO;
        atomicAdd(&cnt_src_ro[src_ro[i]], 1);
        atomicAdd(&cnt_dst_ro[dst_ro[i]], 1);
    } else {
        int i = e - E_OO - E_RO;
        atomicAdd(&cnt_src_ao[src_ao[i]], 1);
        atomicAdd(&cnt_dst_ao[dst_ao[i]], 1);
    }
}

// ---------------------------------------------------------------------------
// Exclusive prefix-sum of the 3 dst-degree arrays
// ---------------------------------------------------------------------------
__global__ __launch_bounds__(1024)
void scan3(const int* c0, const int* c1, const int* c2,
           int* r0, int* r1, int* r2,
           int* u0, int* u1, int* u2)
{
    const int n = N_OBJ;
    const int* cnt = (blockIdx.x == 0) ? c0 : (blockIdx.x == 1 ? c1 : c2);
    int* rp  = (blockIdx.x == 0) ? r0 : (blockIdx.x == 1 ? r1 : r2);
    int* cur = (blockIdx.x == 0) ? u0 : (blockIdx.x == 1 ? u1 : u2);

    __shared__ int part[1024];
    int t  = threadIdx.x;
    int lo = t * 20;
    int hi = lo + 20 < n ? lo + 20 : n;

    int local = 0;
    for (int i = lo; i < hi; ++i) local += cnt[i];
    part[t] = local;
    __syncthreads();
    for (int off = 1; off < 1024; off <<= 1) {
        int v = (t >= off) ? part[t - off] : 0;
        __syncthreads();
        part[t] += v;
        __syncthreads();
    }
    int run = part[t] - local;
    for (int i = lo; i < hi; ++i) {
        rp[i]  = run;
        cur[i] = run;
        run += cnt[i];
    }
    if (t == 1023) rp[n] = part[1023];
}

// ---------------------------------------------------------------------------
// norm = 1/sqrt(max(deg,1)) for the 6 degree arrays
// ---------------------------------------------------------------------------
__global__ void norms6(const int* c0, const int* c1, const int* c2,
                       const int* c3, const int* c4, const int* c5,
                       float* n0, float* n1, float* n2,
                       float* n3, float* n4, float* n5,
                       int s0, int s1, int s2, int s3, int s4, int s5)
{
    const int* c; float* o; int n;
    switch (blockIdx.y) {
        case 0:  c = c0; o = n0; n = s0; break;
        case 1:  c = c1; o = n1; n = s1; break;
        case 2:  c = c2; o = n2; n = s2; break;
        case 3:  c = c3; o = n3; n = s3; break;
        case 4:  c = c4; o = n4; n = s4; break;
        default: c = c5; o = n5; n = s5; break;
    }
    int i = blockIdx.x * blockDim.x + threadIdx.x;
    if (i < n) {
        int d = c[i];
        if (d < 1) d = 1;
        o[i] = 1.0f / sqrtf((float)d);
    }
}

// ---------------------------------------------------------------------------
// Fill CSR column arrays using atomic cursors
// ---------------------------------------------------------------------------
__global__ void fill_edges(const int* __restrict__ src_oo, const int* __restrict__ dst_oo,
                           const int* __restrict__ src_ro, const int* __restrict__ dst_ro,
                           const int* __restrict__ src_ao, const int* __restrict__ dst_ao,
                           int* cur_oo, int* cur_ro, int* cur_ao,
                           int* col_oo, int* col_ro, int* col_ao)
{
    int e = blockIdx.x * blockDim.x + threadIdx.x;
    const int total = E_OO + E_RO + E_AO;
    if (e >= total) return;
    if (e < E_OO) {
        int pos = atomicAdd(&cur_oo[dst_oo[e]], 1);
        col_oo[pos] = src_oo[e];
    } else if (e < E_OO + E_RO) {
        int i = e - E_OO;
        int pos = atomicAdd(&cur_ro[dst_ro[i]], 1);
        col_ro[pos] = src_ro[i];
    } else {
        int i = e - E_OO - E_RO;
        int pos = atomicAdd(&cur_ao[dst_ao[i]], 1);
        col_ao[pos] = src_ao[i];
    }
}

// ---------------------------------------------------------------------------
// Pack weight: Wp is n-major [HDIM][3*Kp] bf16 bits, rows: [Wh | Wl | Wh],
// with optional pre-scale folded in (W2 packed as W2/3).
// ---------------------------------------------------------------------------
__global__ void pack_w(const float* __restrict__ W, int K, int Kp, float scale,
                       unsigned short* __restrict__ Wp)
{
    int Keff = 3 * Kp;
    int idx = blockIdx.x * 256 + threadIdx.x;
    if (idx >= HDIM * Keff) return;
    int n  = idx / Keff;
    int kp = idx - n * Keff;
    int term = (kp >= 2 * Kp) ? 2 : (kp >= Kp ? 1 : 0);
    int ks = kp - term * Kp;
    float v = (ks < K) ? W[(size_t)ks * HDIM + n] * scale : 0.0f;
    unsigned short h = f2bf_rn(v);
    unsigned short out = (term == 1) ? f2bf_rn(v - bf2f(h)) : h;
    Wp[idx] = out;
}

// ---------------------------------------------------------------------------
// Elementwise hi/lo split of a dense [n x K] f32 matrix into [n x Kp] bf16
// pair (pad cols zero). Used for the tiny XW-first GEMM A-sides.
// ---------------------------------------------------------------------------
__global__ void split_feat(const float* __restrict__ X, int n, int K, int Kp,
                           unsigned short* __restrict__ hi, unsigned short* __restrict__ lo)
{
    int idx = blockIdx.x * 256 + threadIdx.x;
    if (idx >= n * Kp) return;
    int r = idx / Kp;
    int c = idx - r * Kp;
    float v = (c < K) ? X[(size_t)r * K + c] : 0.0f;
    unsigned short h = f2bf_rn(v);
    hi[idx] = h;
    lo[idx] = f2bf_rn(v - bf2f(h));
}

// ---------------------------------------------------------------------------
// conv1-oo aggregation: block = one dst node, 128 threads.
// Lanes 0..74 gather float4 (cols 4t..4t+3) of the 300-col f32 row; exactly
// one dwordx4 per active lane per edge. 2-deep pipeline on col->nsrc/feat.
// Per-column accumulation order identical to previous rounds (bit-match).
// Output: hi/lo split, 320-col padded (lanes 75..79 write zero pads).
// ---------------------------------------------------------------------------
__global__ __launch_bounds__(128)
void agg_oo_split(const float* __restrict__ feat,
                  const int* __restrict__ rp, const int* __restrict__ col,
                  const float* __restrict__ nsrc, const float* __restrict__ ndst,
                  unsigned short* __restrict__ hi, unsigned short* __restrict__ lo)
{
    int d = blockIdx.x;
    int t = threadIdx.x;
    int a = rp[d], b = rp[d + 1];
    int n = b - a;
    bool act = (t < 75);                     // 75 * 4 = 300 cols exactly
    const char* fc = (const char*)feat;
    unsigned toff = (unsigned)t * 16u;

    float4 acc = make_float4(0.f, 0.f, 0.f, 0.f);
    int   s1 = (1 < n) ? col[a + 1] : 0;
    int   s0 = (0 < n) ? col[a] : 0;
    float w  = (0 < n) ? nsrc[s0] : 0.f;
    float4 q = make_float4(0.f, 0.f, 0.f, 0.f);
    if (act && 0 < n) q = *(const float4*)(fc + (unsigned)s0 * 1200u + toff);

    for (int j = 0; j < n; ++j) {
        float4 fcur = q; float wc = w;
        int snext = s1;
        s1 = (j + 2 < n) ? col[a + j + 2] : 0;
        if (j + 1 < n) {
            w = nsrc[snext];
            if (act) q = *(const float4*)(fc + (unsigned)snext * 1200u + toff);
        }
        acc.x += fcur.x * wc;
        acc.y += fcur.y * wc;
        acc.z += fcur.z * wc;
        acc.w += fcur.w * wc;
    }

    if (t < 80) {
        float nd = ndst[d];
        float v0 = act ? acc.x * nd : 0.f;
        float v1 = act ? acc.y * nd : 0.f;
        float v2 = act ? acc.z * nd : 0.f;
        float v3 = act ? acc.w * nd : 0.f;
        ushort4 hv, lv;
        hv.x = f2bf_rn(v0); lv.x = f2bf_rn(v0 - bf2f(hv.x));
        hv.y = f2bf_rn(v1); lv.y = f2bf_rn(v1 - bf2f(hv.y));
        hv.z = f2bf_rn(v2); lv.z = f2bf_rn(v2 - bf2f(hv.z));
        hv.w = f2bf_rn(v3); lv.w = f2bf_rn(v3 - bf2f(hv.w));
        size_t o = (size_t)d * 320 + t * 4;
        *(ushort4*)(hi + o) = hv;
        *(ushort4*)(lo + o) = lv;
    }
}

// ---------------------------------------------------------------------------
// 512-col fused aggregation over a dense f32 Y table (row stride 2048 B).
// Block = one dst node, 128 threads; lane t gathers float4 cols 4t..4t+3 --
// exactly one dwordx4 per lane per edge; row offset is a shift (s<<11).
// 2-deep pipeline. v = acc*ndst + bias.
// MODE 0: h_sum += relu(v)                       (ro relation)
// MODE 1: split(h_sum + relu(v)) -> hi2/lo2      (ao relation, fuses conv2 A prep)
// MODE 2: out[slice 0..7] = v                    (conv2 output, ws path)
// MODE 3: out[slice 0]    = v                    (conv2 output, fallback)
// ---------------------------------------------------------------------------
template<int MODE>
__global__ __launch_bounds__(128)
void agg512(const float* __restrict__ Y,
            const int* __restrict__ rp, const int* __restrict__ col,
            const float* __restrict__ nsrc, const float* __restrict__ ndst,
            const float* __restrict__ bias,
            float* __restrict__ hsum,
            unsigned short* __restrict__ hi2, unsigned short* __restrict__ lo2,
            float* __restrict__ out)
{
    int d = blockIdx.x;
    int t = threadIdx.x;
    int a = rp[d], b = rp[d + 1];
    int n = b - a;
    const char* yc = (const char*)Y;
    unsigned toff = (unsigned)t * 16u;

    float4 acc = make_float4(0.f, 0.f, 0.f, 0.f);
    int   s1 = (1 < n) ? col[a + 1] : 0;
    int   s0 = (0 < n) ? col[a] : 0;
    float w  = (0 < n) ? nsrc[s0] : 0.f;
    float4 q = make_float4(0.f, 0.f, 0.f, 0.f);
    if (0 < n) q = *(const float4*)(yc + ((unsigned)s0 << 11) + toff);

    for (int j = 0; j < n; ++j) {
        float4 fcur = q; float wc = w;
        int snext = s1;
        s1 = (j + 2 < n) ? col[a + j + 2] : 0;
        if (j + 1 < n) {
            w = nsrc[snext];
            q = *(const float4*)(yc + ((unsigned)snext << 11) + toff);
        }
        acc.x += fcur.x * wc;
        acc.y += fcur.y * wc;
        acc.z += fcur.z * wc;
        acc.w += fcur.w * wc;
    }

    float nd = ndst[d];
    float4 bv = *(const float4*)(bias + t * 4);
    float4 v;
    v.x = acc.x * nd + bv.x;
    v.y = acc.y * nd + bv.y;
    v.z = acc.z * nd + bv.z;
    v.w = acc.w * nd + bv.w;

    size_t o = (size_t)d * 512 + t * 4;
    if (MODE == 0) {
        float4 old = *(const float4*)(hsum + o);
        old.x += fmaxf(v.x, 0.f);
        old.y += fmaxf(v.y, 0.f);
        old.z += fmaxf(v.z, 0.f);
        old.w += fmaxf(v.w, 0.f);
        *(float4*)(hsum + o) = old;
    } else if (MODE == 1) {
        float4 old = *(const float4*)(hsum + o);
        float h0 = old.x + fmaxf(v.x, 0.f);
        float h1 = old.y + fmaxf(v.y, 0.f);
        float h2 = old.z + fmaxf(v.z, 0.f);
        float h3 = old.w + fmaxf(v.w, 0.f);
        ushort4 hv, lv;
        hv.x = f2bf_rn(h0); lv.x = f2bf_rn(h0 - bf2f(hv.x));
        hv.y = f2bf_rn(h1); lv.y = f2bf_rn(h1 - bf2f(hv.y));
        hv.z = f2bf_rn(h2); lv.z = f2bf_rn(h2 - bf2f(hv.z));
        hv.w = f2bf_rn(h3); lv.w = f2bf_rn(h3 - bf2f(hv.w));
        *(ushort4*)(hi2 + o) = hv;
        *(ushort4*)(lo2 + o) = lv;
    } else if (MODE == 2) {
        const size_t slice = (size_t)N_OBJ * HDIM;
#pragma unroll
        for (int c = 0; c < BATCH; ++c)
            *(float4*)(out + c * slice + o) = v;
    } else {
        *(float4*)(out + o) = v;
    }
}

// ---------------------------------------------------------------------------
// bf16 MFMA GEMM: C[M x 512] = epi( (Ah+Al) @ (Wh+Wl) [+ bias] ), split into
// K_eff = 3*Kp: [0,Kp)=Ah@Wh, [Kp,2Kp)=Ah@Wl, [2Kp,3Kp)=Al@Wh.
// Wp n-major [512][3Kp]. 256 thr = 4 waves, tile 128x128, BK=32.
// global_load_lds width=16 staging (m97); LDT=32 linear, conflict-free.
// OOB A-row reads stay inside ws scratch; rows discarded by m<M guard.
// 1D grid + bijective m204 XCD swizzle.
// EPI: 0 = C=relu(v+b), 1 = C+=relu(v+b), 3 = C=v+b, 4 = C=v (no bias)
// ---------------------------------------------------------------------------
template<int EPI>
__global__ __launch_bounds__(256)
void gemm_mfma(const unsigned short* __restrict__ Ah,
               const unsigned short* __restrict__ Al,
               const unsigned short* __restrict__ Wp,
               const float* __restrict__ bias,
               float* __restrict__ C,
               int M, int Kp, int nwg)
{
    __shared__ unsigned short As[128 * 32];
    __shared__ unsigned short Bs[128 * 32];

    int orig = blockIdx.x;
    int qq8 = nwg >> 3, r8 = nwg & 7, xcd = orig & 7;
    int w = (xcd < r8 ? xcd * (qq8 + 1) : r8 * (qq8 + 1) + (xcd - r8) * qq8) + (orig >> 3);
    int m0 = (w >> 2) * 128;
    int n0 = (w & 3) * 128;

    int tid  = threadIdx.x;
    int lane = tid & 63;
    int wave = tid >> 6;
    int wm = (wave & 1) * 64;
    int wn = (wave >> 1) * 64;
    int Keff = 3 * Kp;
    int rw = lane & 15;
    int q  = lane >> 4;

    int rb  = wave * 32;
    int rl  = lane >> 2;
    int klo = (lane & 3) * 8;

    f32x4 acc[4][4];
#pragma unroll
    for (int i = 0; i < 4; ++i)
#pragma unroll
        for (int j = 0; j < 4; ++j) acc[i][j] = (f32x4)0.0f;

    for (int k0 = 0; k0 < Keff; k0 += 32) {
        int term = (k0 >= 2 * Kp) ? 2 : (k0 >= Kp ? 1 : 0);
        int kb = k0 - ((term == 2) ? 2 * Kp : (term == 1 ? Kp : 0));
        const unsigned short* Asrc = (term == 2) ? Al : Ah;

        gload16(Asrc + (size_t)(m0 + rb + rl) * Kp + kb + klo,        &As[rb * 32]);
        gload16(Asrc + (size_t)(m0 + rb + 16 + rl) * Kp + kb + klo,   &As[(rb + 16) * 32]);
        gload16(Wp   + (size_t)(n0 + rb + rl) * Keff + k0 + klo,      &Bs[rb * 32]);
        gload16(Wp   + (size_t)(n0 + rb + 16 + rl) * Keff + k0 + klo, &Bs[(rb + 16) * 32]);
        __syncthreads();

        bf16x8 af[4], bfr[4];
#pragma unroll
        for (int i = 0; i < 4; ++i) {
            af[i]  = __builtin_bit_cast(bf16x8, *(const uint4*)&As[(wm + i * 16 + rw) * 32 + q * 8]);
            bfr[i] = __builtin_bit_cast(bf16x8, *(const uint4*)&Bs[(wn + i * 16 + rw) * 32 + q * 8]);
        }
#pragma unroll
        for (int i = 0; i < 4; ++i)
#pragma unroll
            for (int j = 0; j < 4; ++j)
                acc[i][j] = __builtin_amdgcn_mfma_f32_16x16x32_bf16(af[i], bfr[j], acc[i][j], 0, 0, 0);
        __syncthreads();
    }

#pragma unroll
    for (int j = 0; j < 4; ++j) {
        int n = n0 + wn + j * 16 + rw;
        float bv = (EPI == 4) ? 0.f : bias[n];
#pragma unroll
        for (int i = 0; i < 4; ++i) {
#pragma unroll
            for (int r = 0; r < 4; ++r) {
                int m = m0 + wm + i * 16 + q * 4 + r;
                if (m < M) {
                    float v = acc[i][j][r] + bv;
                    size_t o = (size_t)m * HDIM + n;
                    if (EPI == 0)      C[o] = fmaxf(v, 0.f);
                    else if (EPI == 1) C[o] += fmaxf(v, 0.f);
                    else               C[o] = v;   // EPI 3 (with bias) / 4 (bv=0)
                }
            }
        }
    }
}

// ---------------------------------------------------------------------------
// Broadcast slice 0 of d_out into slices 1..7 (fallback path only)
// ---------------------------------------------------------------------------
__global__ void bcast8(const float4* __restrict__ src, float4* __restrict__ dst)
{
    const long long slice4 = (long long)N_OBJ * HDIM / 4;
    long long i = (long long)blockIdx.x * blockDim.x + threadIdx.x;
    float4 v = src[i];
#pragma unroll
    for (int c = 1; c < BATCH; ++c)
        dst[c * slice4 + i] = v;
}

// ---------------------------------------------------------------------------
extern "C" void kernel_launch(void* const* d_in, const int* in_sizes, int n_in,
                              void* d_out, int out_size, void* d_ws, size_t ws_size,
                              hipStream_t stream)
{
    const float* feat_object = (const float*)d_in[1];
    const float* feat_room   = (const float*)d_in[2];
    const float* feat_attr   = (const float*)d_in[3];
    const float* W1i = (const float*)d_in[4];
    const float* b1i = (const float*)d_in[5];
    const float* W1b = (const float*)d_in[6];
    const float* b1b = (const float*)d_in[7];
    const float* W2  = (const float*)d_in[8];
    const float* b2  = (const float*)d_in[9];
    const int* src_oo = (const int*)d_in[10];
    const int* dst_oo = (const int*)d_in[11];
    const int* src_ro = (const int*)d_in[12];
    const int* dst_ro = (const int*)d_in[13];
    const int* src_ao = (const int*)d_in[14];
    const int* dst_ao = (const int*)d_in[15];
    float* out = (float*)d_out;

    const size_t slice = (size_t)N_OBJ * HDIM;
    const int KP1 = 320;                 // 300 padded to 32
    const int KP2 = 512;

    const size_t NEED = 200u * 1024u * 1024u;
    bool use_ws = (ws_size >= NEED);
    char* base = use_ws ? (char*)d_ws : (char*)(out + slice);
    size_t off = 0;
    auto alloc = [&](size_t bytes) -> void* {
        void* p = base + off;
        off += (bytes + 255) & ~(size_t)255;
        return p;
    };

    float* n_src_oo = (float*)alloc(N_OBJ  * 4);
    float* n_src_ro = (float*)alloc(N_ROOM * 4);
    float* n_src_ao = (float*)alloc(N_ATTR * 4);
    float* n_dst_oo = (float*)alloc(N_OBJ * 4);
    float* n_dst_ro = (float*)alloc(N_OBJ * 4);
    float* n_dst_ao = (float*)alloc(N_OBJ * 4);

    const int CNT_TOTAL = N_OBJ + 512 + 2048 + 3 * N_OBJ;
    int* cnt_blk    = (int*)alloc((size_t)CNT_TOTAL * 4);
    int* cnt_src_oo = cnt_blk;
    int* cnt_src_ro = cnt_src_oo + N_OBJ;
    int* cnt_src_ao = cnt_src_ro + 512;
    int* cnt_dst_oo = cnt_src_ao + 2048;
    int* cnt_dst_ro = cnt_dst_oo + N_OBJ;
    int* cnt_dst_ao = cnt_dst_ro + N_OBJ;

    int* rp_oo  = (int*)alloc((N_OBJ + 1) * 4);
    int* rp_ro  = (int*)alloc((N_OBJ + 1) * 4);
    int* rp_ao  = (int*)alloc((N_OBJ + 1) * 4);
    int* cur_oo = (int*)alloc(N_OBJ * 4);
    int* cur_ro = (int*)alloc(N_OBJ * 4);
    int* cur_ao = (int*)alloc(N_OBJ * 4);
    int* col_oo = (int*)alloc((size_t)E_OO * 4);
    int* col_ro = (int*)alloc((size_t)E_RO * 4);
    int* col_ao = (int*)alloc((size_t)E_AO * 4);

    unsigned short* Ah1 = (unsigned short*)alloc((size_t)N_OBJ * KP1 * 2);
    unsigned short* Al1 = (unsigned short*)alloc((size_t)N_OBJ * KP1 * 2);
    unsigned short* Ah2 = (unsigned short*)alloc((size_t)N_OBJ * KP2 * 2);
    unsigned short* Al2 = (unsigned short*)alloc((size_t)N_OBJ * KP2 * 2);
    unsigned short* Wp1i = (unsigned short*)alloc((size_t)HDIM * 3 * KP1 * 2);
    unsigned short* Wp1b = (unsigned short*)alloc((size_t)HDIM * 3 * KP1 * 2);
    unsigned short* Wp2  = (unsigned short*)alloc((size_t)HDIM * 3 * KP2 * 2);
    float* h_sum = (float*)alloc(slice * 4);

    unsigned short* Ahr = (unsigned short*)alloc((size_t)N_ROOM * KP1 * 2);
    unsigned short* Alr = (unsigned short*)alloc((size_t)N_ROOM * KP1 * 2);
    unsigned short* Aha = (unsigned short*)alloc((size_t)N_ATTR * KP1 * 2);
    unsigned short* Ala = (unsigned short*)alloc((size_t)N_ATTR * KP1 * 2);
    float* Yro = (float*)alloc((size_t)N_ROOM * HDIM * 4);
    float* Yao = (float*)alloc((size_t)N_ATTR * HDIM * 4);
    float* Y2  = (float*)alloc(slice * 4);

    // ---- CSR build ----
    hipMemsetAsync(cnt_blk, 0, (size_t)CNT_TOTAL * 4, stream);
    const int TOTAL_E = E_OO + E_RO + E_AO;
    int egrid = (TOTAL_E + 255) / 256;
    count_edges<<<egrid, 256, 0, stream>>>(src_oo, dst_oo, src_ro, dst_ro, src_ao, dst_ao,
                                           cnt_src_oo, cnt_src_ro, cnt_src_ao,
                                           cnt_dst_oo, cnt_dst_ro, cnt_dst_ao);
    scan3<<<3, 1024, 0, stream>>>(cnt_dst_oo, cnt_dst_ro, cnt_dst_ao,
                                  rp_oo, rp_ro, rp_ao, cur_oo, cur_ro, cur_ao);
    norms6<<<dim3((N_OBJ + 255) / 256, 6), 256, 0, stream>>>(
        cnt_src_oo, cnt_src_ro, cnt_src_ao, cnt_dst_oo, cnt_dst_ro, cnt_dst_ao,
        n_src_oo, n_src_ro, n_src_ao, n_dst_oo, n_dst_ro, n_dst_ao,
        N_OBJ, N_ROOM, N_ATTR, N_OBJ, N_OBJ, N_OBJ);
    fill_edges<<<egrid, 256, 0, stream>>>(src_oo, dst_oo, src_ro, dst_ro, src_ao, dst_ao,
                                          cur_oo, cur_ro, cur_ao, col_oo, col_ro, col_ao);

    // ---- weight packing (hi/lo split, n-major; W2 folded with 1/3) ----
    {
        int e1 = HDIM * 3 * KP1, e2 = HDIM * 3 * KP2;
        pack_w<<<(e1 + 255) / 256, 256, 0, stream>>>(W1i, IN_F, KP1, 1.0f, Wp1i);
        pack_w<<<(e1 + 255) / 256, 256, 0, stream>>>(W1b, IN_F, KP1, 1.0f, Wp1b);
        pack_w<<<(e2 + 255) / 256, 256, 0, stream>>>(W2, HDIM, KP2, 1.0f / 3.0f, Wp2);
    }

    // ---- tiny XW-first GEMMs for room/attr ----
    split_feat<<<(N_ROOM * KP1 + 255) / 256, 256, 0, stream>>>(feat_room, N_ROOM, IN_F, KP1, Ahr, Alr);
    split_feat<<<(N_ATTR * KP1 + 255) / 256, 256, 0, stream>>>(feat_attr, N_ATTR, IN_F, KP1, Aha, Ala);
    {
        int mtr = (N_ROOM + 127) / 128, nwr = mtr * 4;
        int mta = (N_ATTR + 127) / 128, nwa = mta * 4;
        gemm_mfma<4><<<nwr, 256, 0, stream>>>(Ahr, Alr, Wp1i, b1i, Yro, N_ROOM, KP1, nwr);
        gemm_mfma<4><<<nwa, 256, 0, stream>>>(Aha, Ala, Wp1b, b1b, Yao, N_ATTR, KP1, nwa);
    }

    int mt = (N_OBJ + 127) / 128;
    int nwg = mt * 4;

    // ---- conv1: oo aggregate-first (bit-identical path), ro/ao fused ----
    agg_oo_split<<<N_OBJ, 128, 0, stream>>>(feat_object, rp_oo, col_oo,
                                            n_src_oo, n_dst_oo, Ah1, Al1);
    gemm_mfma<0><<<nwg, 256, 0, stream>>>(Ah1, Al1, Wp1i, b1i, h_sum, N_OBJ, KP1, nwg);

    agg512<0><<<N_OBJ, 128, 0, stream>>>(Yro, rp_ro, col_ro, n_src_ro, n_dst_ro,
                                         b1i, h_sum, nullptr, nullptr, nullptr);
    agg512<1><<<N_OBJ, 128, 0, stream>>>(Yao, rp_ao, col_ao, n_src_ao, n_dst_ao,
                                         b1b, h_sum, Ah2, Al2, nullptr);

    // ---- conv2 XW-first: Y2 = split(h_sum) @ (W2/3); agg -> out (+b2) ----
    gemm_mfma<4><<<nwg, 256, 0, stream>>>(Ah2, Al2, Wp2, b2, Y2, N_OBJ, KP2, nwg);
    if (use_ws) {
        agg512<2><<<N_OBJ, 128, 0, stream>>>(Y2, rp_oo, col_oo, n_src_oo, n_dst_oo,
                                             b2, nullptr, nullptr, nullptr, out);
    } else {
        agg512<3><<<N_OBJ, 128, 0, stream>>>(Y2, rp_oo, col_oo, n_src_oo, n_dst_oo,
                                             b2, nullptr, nullptr, nullptr, out);
        const long long slice4 = (long long)slice / 4;
        bcast8<<<(unsigned)(slice4 / 256), 256, 0, stream>>>((const float4*)out, (float4*)out);
    }
}

// Round 4
// 983.960 us; speedup vs baseline: 1.8299x; 1.0093x over previous
//
#include <hip/hip_runtime.h>

#define N_OBJ  20000
#define N_ROOM 500
#define N_ATTR 2000
#define IN_F   300
#define HDIM   512
#define E_OO   640000
#define E_RO   50000
#define E_AO   100000
#define BATCH  8

typedef __attribute__((ext_vector_type(8))) __bf16 bf16x8;
typedef __attribute__((ext_vector_type(4))) float  f32x4;

// ---- float -> bf16 (round-to-nearest-even), as raw bits ----
__device__ inline unsigned short f2bf_rn(float x)
{
    unsigned u = __float_as_uint(x);
    unsigned r = (u + 0x7fffu + ((u >> 16) & 1u)) >> 16;
    return (unsigned short)r;
}
__device__ inline float bf2f(unsigned short h)
{
    return __uint_as_float(((unsigned)h) << 16);
}

// non-temporal 16B store (bypass L2/L3 -- write-once data must not evict
// the gather tables; gfx950 'nt' flag)
__device__ inline void nt_store_f4(float* p, float4 v)
{
    f32x4 x = {v.x, v.y, v.z, v.w};
    __builtin_nontemporal_store(x, (f32x4*)p);
}

// async global->LDS, 16 B per lane (global addr per-lane, LDS base wave-uniform)
__device__ inline void gload16(const unsigned short* g, unsigned short* l)
{
    __builtin_amdgcn_global_load_lds(
        (const __attribute__((address_space(1))) void*)g,
        (__attribute__((address_space(3))) void*)l,
        16, 0, 0);
}

// ---------------------------------------------------------------------------
// Degree counting (all 3 relations in one grid)
// ---------------------------------------------------------------------------
__global__ void count_edges(const int* __restrict__ src_oo, const int* __restrict__ dst_oo,
                            const int* __restrict__ src_ro, const int* __restrict__ dst_ro,
                            const int* __restrict__ src_ao, const int* __restrict__ dst_ao,
                            int* cnt_src_oo, int* cnt_src_ro, int* cnt_src_ao,
                            int* cnt_dst_oo, int* cnt_dst_ro, int* cnt_dst_ao)
{
    int e = blockIdx.x * blockDim.x + threadIdx.x;
    const int total = E_OO + E_RO + E_AO;
    if (e >= total) return;
    if (e < E_OO) {
        atomicAdd(&cnt_src_oo[src_oo[e]], 1);
        atomicAdd(&cnt_dst_oo[dst_oo[e]], 1);
    } else if (e < E_OO + E_RO) {
        int i = e - E_OO;
        atomicAdd(&cnt_src_ro[src_ro[i]], 1);
        atomicAdd(&cnt_dst_ro[dst_ro[i]], 1);
    } else {
        int i = e - E_OO - E_RO;
        atomicAdd(&cnt_src_ao[src_ao[i]], 1);
        atomicAdd(&cnt_dst_ao[dst_ao[i]], 1);
    }
}

// ---------------------------------------------------------------------------
// Exclusive prefix-sum of the 3 dst-degree arrays
// ---------------------------------------------------------------------------
__global__ __launch_bounds__(1024)
void scan3(const int* c0, const int* c1, const int* c2,
           int* r0, int* r1, int* r2,
           int* u0, int* u1, int* u2)
{
    const int n = N_OBJ;
    const int* cnt = (blockIdx.x == 0) ? c0 : (blockIdx.x == 1 ? c1 : c2);
    int* rp  = (blockIdx.x == 0) ? r0 : (blockIdx.x == 1 ? r1 : r2);
    int* cur = (blockIdx.x == 0) ? u0 : (blockIdx.x == 1 ? u1 : u2);

    __shared__ int part[1024];
    int t  = threadIdx.x;
    int lo = t * 20;
    int hi = lo + 20 < n ? lo + 20 : n;

    int local = 0;
    for (int i = lo; i < hi; ++i) local += cnt[i];
    part[t] = local;
    __syncthreads();
    for (int off = 1; off < 1024; off <<= 1) {
        int v = (t >= off) ? part[t - off] : 0;
        __syncthreads();
        part[t] += v;
        __syncthreads();
    }
    int run = part[t] - local;
    for (int i = lo; i < hi; ++i) {
        rp[i]  = run;
        cur[i] = run;
        run += cnt[i];
    }
    if (t == 1023) rp[n] = part[1023];
}

// ---------------------------------------------------------------------------
// norm = 1/sqrt(max(deg,1)) for the 6 degree arrays
// ---------------------------------------------------------------------------
__global__ void norms6(const int* c0, const int* c1, const int* c2,
                       const int* c3, const int* c4, const int* c5,
                       float* n0, float* n1, float* n2,
                       float* n3, float* n4, float* n5,
                       int s0, int s1, int s2, int s3, int s4, int s5)
{
    const int* c; float* o; int n;
    switch (blockIdx.y) {
        case 0:  c = c0; o = n0; n = s0; break;
        case 1:  c = c1; o = n1; n = s1; break;
        case 2:  c = c2; o = n2; n = s2; break;
        case 3:  c = c3; o = n3; n = s3; break;
        case 4:  c = c4; o = n4; n = s4; break;
        default: c = c5; o = n5; n = s5; break;
    }
    int i = blockIdx.x * blockDim.x + threadIdx.x;
    if (i < n) {
        int d = c[i];
        if (d < 1) d = 1;
        o[i] = 1.0f / sqrtf((float)d);
    }
}

// ---------------------------------------------------------------------------
// Fill CSR column arrays using atomic cursors
// ---------------------------------------------------------------------------
__global__ void fill_edges(const int* __restrict__ src_oo, const int* __restrict__ dst_oo,
                           const int* __restrict__ src_ro, const int* __restrict__ dst_ro,
                           const int* __restrict__ src_ao, const int* __restrict__ dst_ao,
                           int* cur_oo, int* cur_ro, int* cur_ao,
                           int* col_oo, int* col_ro, int* col_ao)
{
    int e = blockIdx.x * blockDim.x + threadIdx.x;
    const int total = E_OO + E_RO + E_AO;
    if (e >= total) return;
    if (e < E_OO) {
        int pos = atomicAdd(&cur_oo[dst_oo[e]], 1);
        col_oo[pos] = src_oo[e];
    } else if (e < E_OO + E_RO) {
        int i = e - E_OO;
        int pos = atomicAdd(&cur_ro[dst_ro[i]], 1);
        col_ro[pos] = src_ro[i];
    } else {
        int i = e - E_OO - E_RO;
        int pos = atomicAdd(&cur_ao[dst_ao[i]], 1);
        col_ao[pos] = src_ao[i];
    }
}

// ---------------------------------------------------------------------------
// Pack weight: Wp is n-major [HDIM][3*Kp] bf16 bits, rows: [Wh | Wl | Wh],
// with optional pre-scale folded in (W2 packed as W2/3).
// ---------------------------------------------------------------------------
__global__ void pack_w(const float* __restrict__ W, int K, int Kp, float scale,
                       unsigned short* __restrict__ Wp)
{
    int Keff = 3 * Kp;
    int idx = blockIdx.x * 256 + threadIdx.x;
    if (idx >= HDIM * Keff) return;
    int n  = idx / Keff;
    int kp = idx - n * Keff;
    int term = (kp >= 2 * Kp) ? 2 : (kp >= Kp ? 1 : 0);
    int ks = kp - term * Kp;
    float v = (ks < K) ? W[(size_t)ks * HDIM + n] * scale : 0.0f;
    unsigned short h = f2bf_rn(v);
    unsigned short out = (term == 1) ? f2bf_rn(v - bf2f(h)) : h;
    Wp[idx] = out;
}

// ---------------------------------------------------------------------------
// Elementwise hi/lo split of a dense [n x K] f32 matrix into [n x Kp] bf16
// pair (pad cols zero). Used for the tiny XW-first GEMM A-sides.
// ---------------------------------------------------------------------------
__global__ void split_feat(const float* __restrict__ X, int n, int K, int Kp,
                           unsigned short* __restrict__ hi, unsigned short* __restrict__ lo)
{
    int idx = blockIdx.x * 256 + threadIdx.x;
    if (idx >= n * Kp) return;
    int r = idx / Kp;
    int c = idx - r * Kp;
    float v = (c < K) ? X[(size_t)r * K + c] : 0.0f;
    unsigned short h = f2bf_rn(v);
    hi[idx] = h;
    lo[idx] = f2bf_rn(v - bf2f(h));
}

// ---------------------------------------------------------------------------
// conv1-oo aggregation: block = one dst node, 128 threads.
// Lanes 0..74 gather float4 (cols 4t..4t+3) of the 300-col f32 row.
// 2-deep pipeline on col->nsrc/feat. Per-column accumulation order identical
// to previous rounds (bit-match). Output: hi/lo split, 320-col padded.
// ---------------------------------------------------------------------------
__global__ __launch_bounds__(128)
void agg_oo_split(const float* __restrict__ feat,
                  const int* __restrict__ rp, const int* __restrict__ col,
                  const float* __restrict__ nsrc, const float* __restrict__ ndst,
                  unsigned short* __restrict__ hi, unsigned short* __restrict__ lo)
{
    int d = blockIdx.x;
    int t = threadIdx.x;
    int a = rp[d], b = rp[d + 1];
    int n = b - a;
    bool act = (t < 75);                     // 75 * 4 = 300 cols exactly
    const char* fc = (const char*)feat;
    unsigned toff = (unsigned)t * 16u;

    float4 acc = make_float4(0.f, 0.f, 0.f, 0.f);
    int   s1 = (1 < n) ? col[a + 1] : 0;
    int   s0 = (0 < n) ? col[a] : 0;
    float w  = (0 < n) ? nsrc[s0] : 0.f;
    float4 q = make_float4(0.f, 0.f, 0.f, 0.f);
    if (act && 0 < n) q = *(const float4*)(fc + (unsigned)s0 * 1200u + toff);

    for (int j = 0; j < n; ++j) {
        float4 fcur = q; float wc = w;
        int snext = s1;
        s1 = (j + 2 < n) ? col[a + j + 2] : 0;
        if (j + 1 < n) {
            w = nsrc[snext];
            if (act) q = *(const float4*)(fc + (unsigned)snext * 1200u + toff);
        }
        acc.x += fcur.x * wc;
        acc.y += fcur.y * wc;
        acc.z += fcur.z * wc;
        acc.w += fcur.w * wc;
    }

    if (t < 80) {
        float nd = ndst[d];
        float v0 = act ? acc.x * nd : 0.f;
        float v1 = act ? acc.y * nd : 0.f;
        float v2 = act ? acc.z * nd : 0.f;
        float v3 = act ? acc.w * nd : 0.f;
        ushort4 hv, lv;
        hv.x = f2bf_rn(v0); lv.x = f2bf_rn(v0 - bf2f(hv.x));
        hv.y = f2bf_rn(v1); lv.y = f2bf_rn(v1 - bf2f(hv.y));
        hv.z = f2bf_rn(v2); lv.z = f2bf_rn(v2 - bf2f(hv.z));
        hv.w = f2bf_rn(v3); lv.w = f2bf_rn(v3 - bf2f(hv.w));
        size_t o = (size_t)d * 320 + t * 4;
        *(ushort4*)(hi + o) = hv;
        *(ushort4*)(lo + o) = lv;
    }
}

// ---------------------------------------------------------------------------
// Fused ro+ao aggregation over the two dense XW tables (512 cols, f32).
// Block = one dst node, 128 threads; lane t owns cols 4t..4t+3.
// h = h_sum + relu(agg_ro*nd_ro + b1i) + relu(agg_ao*nd_ao + b1b), then
// hi/lo split -> conv2 A operand. Same add order as the unfused pair.
// ---------------------------------------------------------------------------
__global__ __launch_bounds__(128)
void agg_roao(const float* __restrict__ Yro, const float* __restrict__ Yao,
              const int* __restrict__ rp_ro, const int* __restrict__ col_ro,
              const int* __restrict__ rp_ao, const int* __restrict__ col_ao,
              const float* __restrict__ ns_ro, const float* __restrict__ nd_ro,
              const float* __restrict__ ns_ao, const float* __restrict__ nd_ao,
              const float* __restrict__ b_ro, const float* __restrict__ b_ao,
              const float* __restrict__ hsum,
              unsigned short* __restrict__ hi2, unsigned short* __restrict__ lo2)
{
    int d = blockIdx.x;
    int t = threadIdx.x;
    unsigned toff = (unsigned)t * 16u;

    // ---- ro relation ----
    float4 accr = make_float4(0.f, 0.f, 0.f, 0.f);
    {
        int a = rp_ro[d], b = rp_ro[d + 1];
        int n = b - a;
        const char* yc = (const char*)Yro;
        int   s1 = (1 < n) ? col_ro[a + 1] : 0;
        int   s0 = (0 < n) ? col_ro[a] : 0;
        float w  = (0 < n) ? ns_ro[s0] : 0.f;
        float4 q = make_float4(0.f, 0.f, 0.f, 0.f);
        if (0 < n) q = *(const float4*)(yc + ((unsigned)s0 << 11) + toff);
        for (int j = 0; j < n; ++j) {
            float4 fcur = q; float wc = w;
            int snext = s1;
            s1 = (j + 2 < n) ? col_ro[a + j + 2] : 0;
            if (j + 1 < n) {
                w = ns_ro[snext];
                q = *(const float4*)(yc + ((unsigned)snext << 11) + toff);
            }
            accr.x += fcur.x * wc;
            accr.y += fcur.y * wc;
            accr.z += fcur.z * wc;
            accr.w += fcur.w * wc;
        }
    }

    // ---- ao relation ----
    float4 acca = make_float4(0.f, 0.f, 0.f, 0.f);
    {
        int a = rp_ao[d], b = rp_ao[d + 1];
        int n = b - a;
        const char* yc = (const char*)Yao;
        int   s1 = (1 < n) ? col_ao[a + 1] : 0;
        int   s0 = (0 < n) ? col_ao[a] : 0;
        float w  = (0 < n) ? ns_ao[s0] : 0.f;
        float4 q = make_float4(0.f, 0.f, 0.f, 0.f);
        if (0 < n) q = *(const float4*)(yc + ((unsigned)s0 << 11) + toff);
        for (int j = 0; j < n; ++j) {
            float4 fcur = q; float wc = w;
            int snext = s1;
            s1 = (j + 2 < n) ? col_ao[a + j + 2] : 0;
            if (j + 1 < n) {
                w = ns_ao[snext];
                q = *(const float4*)(yc + ((unsigned)snext << 11) + toff);
            }
            acca.x += fcur.x * wc;
            acca.y += fcur.y * wc;
            acca.z += fcur.z * wc;
            acca.w += fcur.w * wc;
        }
    }

    float ndr = nd_ro[d], nda = nd_ao[d];
    float4 br = *(const float4*)(b_ro + t * 4);
    float4 ba = *(const float4*)(b_ao + t * 4);
    size_t o = (size_t)d * 512 + t * 4;
    float4 old = *(const float4*)(hsum + o);

    float h0 = old.x + fmaxf(accr.x * ndr + br.x, 0.f) + fmaxf(acca.x * nda + ba.x, 0.f);
    float h1 = old.y + fmaxf(accr.y * ndr + br.y, 0.f) + fmaxf(acca.y * nda + ba.y, 0.f);
    float h2 = old.z + fmaxf(accr.z * ndr + br.z, 0.f) + fmaxf(acca.z * nda + ba.z, 0.f);
    float h3 = old.w + fmaxf(accr.w * ndr + br.w, 0.f) + fmaxf(acca.w * nda + ba.w, 0.f);

    ushort4 hv, lv;
    hv.x = f2bf_rn(h0); lv.x = f2bf_rn(h0 - bf2f(hv.x));
    hv.y = f2bf_rn(h1); lv.y = f2bf_rn(h1 - bf2f(hv.y));
    hv.z = f2bf_rn(h2); lv.z = f2bf_rn(h2 - bf2f(hv.z));
    hv.w = f2bf_rn(h3); lv.w = f2bf_rn(h3 - bf2f(hv.w));
    *(ushort4*)(hi2 + o) = hv;
    *(ushort4*)(lo2 + o) = lv;
}

// ---------------------------------------------------------------------------
// conv2 output aggregation over dense Y2 (512 cols f32, row stride 2 KB).
// Block = one dst, 128 threads, one dwordx4 per lane per edge, 2-deep
// pipeline. v = acc*ndst + b2. All out stores NON-TEMPORAL: 328 MB of
// write-once data must not evict Y2 (41 MB, L3-resident) between gathers.
// MODE 2: out[slice 0..7] = v   MODE 3: out[slice 0] = v (fallback)
// ---------------------------------------------------------------------------
template<int MODE>
__global__ __launch_bounds__(128)
void agg512(const float* __restrict__ Y,
            const int* __restrict__ rp, const int* __restrict__ col,
            const float* __restrict__ nsrc, const float* __restrict__ ndst,
            const float* __restrict__ bias,
            float* __restrict__ out)
{
    int d = blockIdx.x;
    int t = threadIdx.x;
    int a = rp[d], b = rp[d + 1];
    int n = b - a;
    const char* yc = (const char*)Y;
    unsigned toff = (unsigned)t * 16u;

    float4 acc = make_float4(0.f, 0.f, 0.f, 0.f);
    int   s1 = (1 < n) ? col[a + 1] : 0;
    int   s0 = (0 < n) ? col[a] : 0;
    float w  = (0 < n) ? nsrc[s0] : 0.f;
    float4 q = make_float4(0.f, 0.f, 0.f, 0.f);
    if (0 < n) q = *(const float4*)(yc + ((unsigned)s0 << 11) + toff);

    for (int j = 0; j < n; ++j) {
        float4 fcur = q; float wc = w;
        int snext = s1;
        s1 = (j + 2 < n) ? col[a + j + 2] : 0;
        if (j + 1 < n) {
            w = nsrc[snext];
            q = *(const float4*)(yc + ((unsigned)snext << 11) + toff);
        }
        acc.x += fcur.x * wc;
        acc.y += fcur.y * wc;
        acc.z += fcur.z * wc;
        acc.w += fcur.w * wc;
    }

    float nd = ndst[d];
    float4 bv = *(const float4*)(bias + t * 4);
    float4 v;
    v.x = acc.x * nd + bv.x;
    v.y = acc.y * nd + bv.y;
    v.z = acc.z * nd + bv.z;
    v.w = acc.w * nd + bv.w;

    size_t o = (size_t)d * 512 + t * 4;
    if (MODE == 2) {
        const size_t slice = (size_t)N_OBJ * HDIM;
#pragma unroll
        for (int c = 0; c < BATCH; ++c)
            nt_store_f4(out + c * slice + o, v);
    } else {
        nt_store_f4(out + o, v);
    }
}

// ---------------------------------------------------------------------------
// bf16 MFMA GEMM: C[M x 512] = epi( (Ah+Al) @ (Wh+Wl) [+ bias] ), split into
// K_eff = 3*Kp: [0,Kp)=Ah@Wh, [Kp,2Kp)=Ah@Wl, [2Kp,3Kp)=Al@Wh.
// Wp n-major [512][3Kp]. 256 thr = 4 waves, tile 128x128, BK=32.
// global_load_lds width=16 staging (m97); LDT=32 linear, conflict-free.
// OOB A-row reads stay inside ws scratch; rows discarded by m<M guard.
// 1D grid + bijective m204 XCD swizzle.
// EPI: 0 = C=relu(v+b), 1 = C+=relu(v+b), 3 = C=v+b, 4 = C=v (no bias)
// ---------------------------------------------------------------------------
template<int EPI>
__global__ __launch_bounds__(256)
void gemm_mfma(const unsigned short* __restrict__ Ah,
               const unsigned short* __restrict__ Al,
               const unsigned short* __restrict__ Wp,
               const float* __restrict__ bias,
               float* __restrict__ C,
               int M, int Kp, int nwg)
{
    __shared__ unsigned short As[128 * 32];
    __shared__ unsigned short Bs[128 * 32];

    int orig = blockIdx.x;
    int qq8 = nwg >> 3, r8 = nwg & 7, xcd = orig & 7;
    int w = (xcd < r8 ? xcd * (qq8 + 1) : r8 * (qq8 + 1) + (xcd - r8) * qq8) + (orig >> 3);
    int m0 = (w >> 2) * 128;
    int n0 = (w & 3) * 128;

    int tid  = threadIdx.x;
    int lane = tid & 63;
    int wave = tid >> 6;
    int wm = (wave & 1) * 64;
    int wn = (wave >> 1) * 64;
    int Keff = 3 * Kp;
    int rw = lane & 15;
    int q  = lane >> 4;

    int rb  = wave * 32;
    int rl  = lane >> 2;
    int klo = (lane & 3) * 8;

    f32x4 acc[4][4];
#pragma unroll
    for (int i = 0; i < 4; ++i)
#pragma unroll
        for (int j = 0; j < 4; ++j) acc[i][j] = (f32x4)0.0f;

    for (int k0 = 0; k0 < Keff; k0 += 32) {
        int term = (k0 >= 2 * Kp) ? 2 : (k0 >= Kp ? 1 : 0);
        int kb = k0 - ((term == 2) ? 2 * Kp : (term == 1 ? Kp : 0));
        const unsigned short* Asrc = (term == 2) ? Al : Ah;

        gload16(Asrc + (size_t)(m0 + rb + rl) * Kp + kb + klo,        &As[rb * 32]);
        gload16(Asrc + (size_t)(m0 + rb + 16 + rl) * Kp + kb + klo,   &As[(rb + 16) * 32]);
        gload16(Wp   + (size_t)(n0 + rb + rl) * Keff + k0 + klo,      &Bs[rb * 32]);
        gload16(Wp   + (size_t)(n0 + rb + 16 + rl) * Keff + k0 + klo, &Bs[(rb + 16) * 32]);
        __syncthreads();

        bf16x8 af[4], bfr[4];
#pragma unroll
        for (int i = 0; i < 4; ++i) {
            af[i]  = __builtin_bit_cast(bf16x8, *(const uint4*)&As[(wm + i * 16 + rw) * 32 + q * 8]);
            bfr[i] = __builtin_bit_cast(bf16x8, *(const uint4*)&Bs[(wn + i * 16 + rw) * 32 + q * 8]);
        }
#pragma unroll
        for (int i = 0; i < 4; ++i)
#pragma unroll
            for (int j = 0; j < 4; ++j)
                acc[i][j] = __builtin_amdgcn_mfma_f32_16x16x32_bf16(af[i], bfr[j], acc[i][j], 0, 0, 0);
        __syncthreads();
    }

#pragma unroll
    for (int j = 0; j < 4; ++j) {
        int n = n0 + wn + j * 16 + rw;
        float bv = (EPI == 4) ? 0.f : bias[n];
#pragma unroll
        for (int i = 0; i < 4; ++i) {
#pragma unroll
            for (int r = 0; r < 4; ++r) {
                int m = m0 + wm + i * 16 + q * 4 + r;
                if (m < M) {
                    float v = acc[i][j][r] + bv;
                    size_t o = (size_t)m * HDIM + n;
                    if (EPI == 0)      C[o] = fmaxf(v, 0.f);
                    else if (EPI == 1) C[o] += fmaxf(v, 0.f);
                    else               C[o] = v;   // EPI 3 (with bias) / 4 (bv=0)
                }
            }
        }
    }
}

// ---------------------------------------------------------------------------
// Broadcast slice 0 of d_out into slices 1..7 (fallback path only)
// ---------------------------------------------------------------------------
__global__ void bcast8(const float* __restrict__ src, float* __restrict__ dst)
{
    const long long slice = (long long)N_OBJ * HDIM;
    long long i = ((long long)blockIdx.x * blockDim.x + threadIdx.x) * 4;
    float4 v = *(const float4*)(src + i);
#pragma unroll
    for (int c = 1; c < BATCH; ++c)
        nt_store_f4(dst + c * slice + i, v);
}

// ---------------------------------------------------------------------------
extern "C" void kernel_launch(void* const* d_in, const int* in_sizes, int n_in,
                              void* d_out, int out_size, void* d_ws, size_t ws_size,
                              hipStream_t stream)
{
    const float* feat_object = (const float*)d_in[1];
    const float* feat_room   = (const float*)d_in[2];
    const float* feat_attr   = (const float*)d_in[3];
    const float* W1i = (const float*)d_in[4];
    const float* b1i = (const float*)d_in[5];
    const float* W1b = (const float*)d_in[6];
    const float* b1b = (const float*)d_in[7];
    const float* W2  = (const float*)d_in[8];
    const float* b2  = (const float*)d_in[9];
    const int* src_oo = (const int*)d_in[10];
    const int* dst_oo = (const int*)d_in[11];
    const int* src_ro = (const int*)d_in[12];
    const int* dst_ro = (const int*)d_in[13];
    const int* src_ao = (const int*)d_in[14];
    const int* dst_ao = (const int*)d_in[15];
    float* out = (float*)d_out;

    const size_t slice = (size_t)N_OBJ * HDIM;
    const int KP1 = 320;                 // 300 padded to 32
    const int KP2 = 512;

    const size_t NEED = 200u * 1024u * 1024u;
    bool use_ws = (ws_size >= NEED);
    char* base = use_ws ? (char*)d_ws : (char*)(out + slice);
    size_t off = 0;
    auto alloc = [&](size_t bytes) -> void* {
        void* p = base + off;
        off += (bytes + 255) & ~(size_t)255;
        return p;
    };

    float* n_src_oo = (float*)alloc(N_OBJ  * 4);
    float* n_src_ro = (float*)alloc(N_ROOM * 4);
    float* n_src_ao = (float*)alloc(N_ATTR * 4);
    float* n_dst_oo = (float*)alloc(N_OBJ * 4);
    float* n_dst_ro = (float*)alloc(N_OBJ * 4);
    float* n_dst_ao = (float*)alloc(N_OBJ * 4);

    const int CNT_TOTAL = N_OBJ + 512 + 2048 + 3 * N_OBJ;
    int* cnt_blk    = (int*)alloc((size_t)CNT_TOTAL * 4);
    int* cnt_src_oo = cnt_blk;
    int* cnt_src_ro = cnt_src_oo + N_OBJ;
    int* cnt_src_ao = cnt_src_ro + 512;
    int* cnt_dst_oo = cnt_src_ao + 2048;
    int* cnt_dst_ro = cnt_dst_oo + N_OBJ;
    int* cnt_dst_ao = cnt_dst_ro + N_OBJ;

    int* rp_oo  = (int*)alloc((N_OBJ + 1) * 4);
    int* rp_ro  = (int*)alloc((N_OBJ + 1) * 4);
    int* rp_ao  = (int*)alloc((N_OBJ + 1) * 4);
    int* cur_oo = (int*)alloc(N_OBJ * 4);
    int* cur_ro = (int*)alloc(N_OBJ * 4);
    int* cur_ao = (int*)alloc(N_OBJ * 4);
    int* col_oo = (int*)alloc((size_t)E_OO * 4);
    int* col_ro = (int*)alloc((size_t)E_RO * 4);
    int* col_ao = (int*)alloc((size_t)E_AO * 4);

    unsigned short* Ah1 = (unsigned short*)alloc((size_t)N_OBJ * KP1 * 2);
    unsigned short* Al1 = (unsigned short*)alloc((size_t)N_OBJ * KP1 * 2);
    unsigned short* Ah2 = (unsigned short*)alloc((size_t)N_OBJ * KP2 * 2);
    unsigned short* Al2 = (unsigned short*)alloc((size_t)N_OBJ * KP2 * 2);
    unsigned short* Wp1i = (unsigned short*)alloc((size_t)HDIM * 3 * KP1 * 2);
    unsigned short* Wp1b = (unsigned short*)alloc((size_t)HDIM * 3 * KP1 * 2);
    unsigned short* Wp2  = (unsigned short*)alloc((size_t)HDIM * 3 * KP2 * 2);
    float* h_sum = (float*)alloc(slice * 4);

    unsigned short* Ahr = (unsigned short*)alloc((size_t)N_ROOM * KP1 * 2);
    unsigned short* Alr = (unsigned short*)alloc((size_t)N_ROOM * KP1 * 2);
    unsigned short* Aha = (unsigned short*)alloc((size_t)N_ATTR * KP1 * 2);
    unsigned short* Ala = (unsigned short*)alloc((size_t)N_ATTR * KP1 * 2);
    float* Yro = (float*)alloc((size_t)N_ROOM * HDIM * 4);
    float* Yao = (float*)alloc((size_t)N_ATTR * HDIM * 4);
    float* Y2  = (float*)alloc(slice * 4);

    // ---- CSR build ----
    hipMemsetAsync(cnt_blk, 0, (size_t)CNT_TOTAL * 4, stream);
    const int TOTAL_E = E_OO + E_RO + E_AO;
    int egrid = (TOTAL_E + 255) / 256;
    count_edges<<<egrid, 256, 0, stream>>>(src_oo, dst_oo, src_ro, dst_ro, src_ao, dst_ao,
                                           cnt_src_oo, cnt_src_ro, cnt_src_ao,
                                           cnt_dst_oo, cnt_dst_ro, cnt_dst_ao);
    scan3<<<3, 1024, 0, stream>>>(cnt_dst_oo, cnt_dst_ro, cnt_dst_ao,
                                  rp_oo, rp_ro, rp_ao, cur_oo, cur_ro, cur_ao);
    norms6<<<dim3((N_OBJ + 255) / 256, 6), 256, 0, stream>>>(
        cnt_src_oo, cnt_src_ro, cnt_src_ao, cnt_dst_oo, cnt_dst_ro, cnt_dst_ao,
        n_src_oo, n_src_ro, n_src_ao, n_dst_oo, n_dst_ro, n_dst_ao,
        N_OBJ, N_ROOM, N_ATTR, N_OBJ, N_OBJ, N_OBJ);
    fill_edges<<<egrid, 256, 0, stream>>>(src_oo, dst_oo, src_ro, dst_ro, src_ao, dst_ao,
                                          cur_oo, cur_ro, cur_ao, col_oo, col_ro, col_ao);

    // ---- weight packing (hi/lo split, n-major; W2 folded with 1/3) ----
    {
        int e1 = HDIM * 3 * KP1, e2 = HDIM * 3 * KP2;
        pack_w<<<(e1 + 255) / 256, 256, 0, stream>>>(W1i, IN_F, KP1, 1.0f, Wp1i);
        pack_w<<<(e1 + 255) / 256, 256, 0, stream>>>(W1b, IN_F, KP1, 1.0f, Wp1b);
        pack_w<<<(e2 + 255) / 256, 256, 0, stream>>>(W2, HDIM, KP2, 1.0f / 3.0f, Wp2);
    }

    // ---- tiny XW-first GEMMs for room/attr ----
    split_feat<<<(N_ROOM * KP1 + 255) / 256, 256, 0, stream>>>(feat_room, N_ROOM, IN_F, KP1, Ahr, Alr);
    split_feat<<<(N_ATTR * KP1 + 255) / 256, 256, 0, stream>>>(feat_attr, N_ATTR, IN_F, KP1, Aha, Ala);
    {
        int mtr = (N_ROOM + 127) / 128, nwr = mtr * 4;
        int mta = (N_ATTR + 127) / 128, nwa = mta * 4;
        gemm_mfma<4><<<nwr, 256, 0, stream>>>(Ahr, Alr, Wp1i, b1i, Yro, N_ROOM, KP1, nwr);
        gemm_mfma<4><<<nwa, 256, 0, stream>>>(Aha, Ala, Wp1b, b1b, Yao, N_ATTR, KP1, nwa);
    }

    int mt = (N_OBJ + 127) / 128;
    int nwg = mt * 4;

    // ---- conv1: oo aggregate-first (bit-identical path), ro/ao fused ----
    agg_oo_split<<<N_OBJ, 128, 0, stream>>>(feat_object, rp_oo, col_oo,
                                            n_src_oo, n_dst_oo, Ah1, Al1);
    gemm_mfma<0><<<nwg, 256, 0, stream>>>(Ah1, Al1, Wp1i, b1i, h_sum, N_OBJ, KP1, nwg);

    agg_roao<<<N_OBJ, 128, 0, stream>>>(Yro, Yao, rp_ro, col_ro, rp_ao, col_ao,
                                        n_src_ro, n_dst_ro, n_src_ao, n_dst_ao,
                                        b1i, b1b, h_sum, Ah2, Al2);

    // ---- conv2 XW-first: Y2 = split(h_sum) @ (W2/3); agg -> out (+b2) ----
    gemm_mfma<4><<<nwg, 256, 0, stream>>>(Ah2, Al2, Wp2, b2, Y2, N_OBJ, KP2, nwg);
    if (use_ws) {
        agg512<2><<<N_OBJ, 128, 0, stream>>>(Y2, rp_oo, col_oo, n_src_oo, n_dst_oo, b2, out);
    } else {
        agg512<3><<<N_OBJ, 128, 0, stream>>>(Y2, rp_oo, col_oo, n_src_oo, n_dst_oo, b2, out);
        const long long slice4 = (long long)slice / 4;
        bcast8<<<(unsigned)(slice4 / 256), 256, 0, stream>>>(out, out);
    }
}